// Round 13
// baseline (1699.060 us; speedup 1.0000x reference)
//
#include <hip/hip_runtime.h>
#include <hip/hip_bf16.h>

#define NATOM 100000
#define MNBR  12
#define FDIM  64
#define BDIM  41
#define C2    128
#define EPSBN 1e-5f
#define NEDGE (NATOM * MNBR)   // 1,200,000
#define KP48  48               // nbr packed width (41 real + 7 zero), 96B rows
#define NFRAG  16384           // edge B frag-linear: 8T * 4s * 64l * 8e (rows 64..168)
#define NFRAGS 8192            // self B frag-linear: 8T * 2s * 64l * 8e (rows 0..63)

typedef __attribute__((ext_vector_type(8))) short bf16x8;
typedef __attribute__((ext_vector_type(4))) float f32x4;

// ---- ws layout (float units) ----
#define X_OFF    0L            // x: N*64 f32 (master)
#define XB_OFF   6400000L      // xb: N*64 bf16
#define S_OFF    9600000L      // nbr_sumed: N*64 f32
#define NBRB_OFF 16000000L     // nbr bf16 packed 48-wide: 1.2M*48 bf16 (28.8M floats)
#define AS_OFF   54400000L     // a = x@W_self: N*128 bf16 (6.4M floats)
#define BALL_OFF 60800000L     // edge B frag bf16: 16384 elems (8192 floats)
#define BALLS_OFF 60808192L    // self B frag bf16: 8192 elems (4096 floats)
#define BN1S_OFF 60812288L     // 64 slots * 256
#define BN2S_OFF 60828672L     // 64 slots * 128
#define SC1_OFF  60836864L
#define SH1_OFF  60836992L
#define SC2_OFF  60837120L
#define SH2_OFF  60837184L
#define CRY_OFF  60837248L     // 2000*64
#define CNT_OFF  60965248L     // 2000
#define ZERO_OFF BN1S_OFF
#define ZERO_CNT 154960L

__device__ __forceinline__ float bf2f(unsigned short u) {
    return __uint_as_float(((unsigned)u) << 16);
}
__device__ __forceinline__ float softplus_f(float v) {
    return fmaxf(v, 0.f) + __logf(1.f + __expf(-fabsf(v)));
}

__global__ void k_zero(float* __restrict__ p, long cnt) {
    long i = (long)blockIdx.x * 256 + threadIdx.x;
    if (i < cnt) p[i] = 0.f;
}

// nbr_fea f32 [1.2M][41] -> bf16 [1.2M][48] zero-padded; short8-vectorized writes
__global__ void k_nbrcvt(const float* __restrict__ nbr, __hip_bfloat16* __restrict__ outb) {
    long i = (long)blockIdx.x * 256 + threadIdx.x;   // one 8-elem chunk each
    if (i >= (long)NEDGE * 6) return;
    long e = i / 6;
    int c = (int)(i - e * 6);
    const float* src = nbr + e * BDIM + c * 8;
    bf16x8 v;
#pragma unroll
    for (int j = 0; j < 8; ++j) {
        int k = c * 8 + j;
        float f = (k < BDIM) ? src[j] : 0.f;
        __hip_bfloat16 h = __float2bfloat16(f);
        v[j] = *(short*)&h;
    }
    *(bf16x8*)((short*)outb + e * KP48 + c * 8) = v;
}

// Fragment-linear B for both GEMMs.
// edge  (K=128, W rows 64..168): ballf [((T*4+s)*64+l)*8+e] = W[64+s*32+(l>>4)*8+e][T*16+(l&15)]
// self  (K=64,  W rows  0..63 ): ballfS[((T*2+s)*64+l)*8+e] = W[   s*32+(l>>4)*8+e][T*16+(l&15)]
__global__ void k_bcvt(const float* __restrict__ cw, __hip_bfloat16* __restrict__ ballf,
                       __hip_bfloat16* __restrict__ ballfS) {
    int i = blockIdx.x * 256 + threadIdx.x;
    if (i < NFRAG) {
        int T = i / 2048, r = i - T * 2048;
        int lidx = (r >> 3) & 63, e = i & 7;
        int s4 = r >> 9;
        int lo = lidx & 15, hi = lidx >> 4;
        int krow = 64 + s4 * 32 + hi * 8 + e;
        float v = (krow < 169) ? cw[krow * C2 + T * 16 + lo] : 0.f;
        ballf[i] = __float2bfloat16(v);
    } else if (i < NFRAG + NFRAGS) {
        int i2 = i - NFRAG;
        int T = i2 / 1024, r = i2 - T * 1024;
        int lidx = (r >> 3) & 63, e = i2 & 7;
        int s = r >> 9;
        int lo = lidx & 15, hi = lidx >> 4;
        int krow = s * 32 + hi * 8 + e;   // 0..63
        ballfS[i2] = __float2bfloat16(cw[krow * C2 + T * 16 + lo]);
    }
}

__global__ __launch_bounds__(256)
void k_embed(const float* __restrict__ af, const float* __restrict__ ew,
             const float* __restrict__ eb, float* __restrict__ x,
             __hip_bfloat16* __restrict__ xb) {
    int t = threadIdx.x;
    int c = t & 63, ag = t >> 6;
    long n0 = (long)blockIdx.x * 16 + ag * 4;
    float acc[4] = {0.f, 0.f, 0.f, 0.f};
    for (int k4 = 0; k4 < 23; ++k4) {
        float w0 = ew[(4 * k4 + 0) * FDIM + c];
        float w1 = ew[(4 * k4 + 1) * FDIM + c];
        float w2 = ew[(4 * k4 + 2) * FDIM + c];
        float w3 = ew[(4 * k4 + 3) * FDIM + c];
#pragma unroll
        for (int a = 0; a < 4; ++a) {
            const float4* ar = (const float4*)(af + (n0 + a) * 92);
            float4 v = ar[k4];
            acc[a] += v.x * w0 + v.y * w1 + v.z * w2 + v.w * w3;
        }
    }
    float b = eb[c];
#pragma unroll
    for (int a = 0; a < 4; ++a) {
        float v = acc[a] + b;
        x[(n0 + a) * FDIM + c] = v;
        xb[(n0 + a) * FDIM + c] = __float2bfloat16(v);
    }
}

// aS = xb @ W_self via MFMA: one 16-atom tile per wave (A rows = atoms).
__global__ __launch_bounds__(256, 8)
void k_lin(const __hip_bfloat16* __restrict__ xb, const __hip_bfloat16* __restrict__ ballfS,
           __hip_bfloat16* __restrict__ aS) {
    int t = threadIdx.x, w = t >> 6, l = t & 63;
    int lo = l & 15, hi = l >> 4;
    long atom0 = ((long)blockIdx.x * 4 + w) * 16;
    if (atom0 >= NATOM) return;
    const short* xs = (const short*)xb + (atom0 + lo) * FDIM + hi * 8;
    bf16x8 A0 = *(const bf16x8*)(xs);
    bf16x8 A1 = *(const bf16x8*)(xs + 32);
    const short* bS = (const short*)ballfS;
#pragma unroll
    for (int T = 0; T < 8; ++T) {
        bf16x8 B0 = *(const bf16x8*)(bS + T * 1024 + l * 8);
        bf16x8 B1 = *(const bf16x8*)(bS + T * 1024 + 512 + l * 8);
        f32x4 z = {0.f, 0.f, 0.f, 0.f};
        z = __builtin_amdgcn_mfma_f32_16x16x32_bf16(A0, B0, z, 0, 0, 0);
        z = __builtin_amdgcn_mfma_f32_16x16x32_bf16(A1, B1, z, 0, 0, 0);
#pragma unroll
        for (int qq = 0; qq < 4; ++qq)
            aS[(atom0 + hi * 4 + qq) * C2 + T * 16 + lo] = __float2bfloat16(z[qq]);
    }
}

// Edge kernel (r8 structure + 48-wide nbr + 8 waves/EU): one atom per 16x16
// MFMA tile (12 real rows + 4 pads, masked), K=128 ([x[j] | nbr48]); self term
// folded into epilogue; B straight from global (L2-hot); 2-atom pairs keep A
// live-range at 32 VGPR. VGPR must stay <=64 for 8 waves/SIMD.
template <int APPLY>
__global__ __launch_bounds__(256, 8)
void k_edge(const __hip_bfloat16* __restrict__ xb,
            const __hip_bfloat16* __restrict__ nbrb,
            const __hip_bfloat16* __restrict__ ballf,
            const __hip_bfloat16* __restrict__ aS,
            const int* __restrict__ idxp,
            const float* __restrict__ sc1, const float* __restrict__ sh1,
            float* __restrict__ bn1_slots,
            float* __restrict__ sout, float* __restrict__ bn2_slots) {
    __shared__ float bn_s[256];
    __shared__ float sc_s[128], sh_s[128];

    const int t = threadIdx.x;
    const int w = t >> 6, l = t & 63;
    const int lo = l & 15, hi = l >> 4;
    const bool real = lo < MNBR;
    const int elo = real ? lo : 0;           // clamp pad lanes in-bounds
    const int atom0 = blockIdx.x * 16 + w * 4;
    const short* xbS = (const short*)xb;
    const short* nbS = (const short*)nbrb;
    const short* aSS = (const short*)aS;
    const short* bb  = (const short*)ballf;

    bn_s[t] = 0.f;
    if (APPLY && t < 128) { sc_s[t] = sc1[t]; sh_s[t] = sh1[t]; }
    __syncthreads();

    const bf16x8 zz = {0, 0, 0, 0, 0, 0, 0, 0};
    const int off1 = (hi < 2) ? (32 + hi * 8) : 0;   // slice-1 source (k=32..47) or dummy

#pragma unroll 1
    for (int pr = 0; pr < 2; ++pr) {
        const int a0 = atom0 + pr * 2;
        const int a1 = a0 + 1;
        const int j0 = idxp[(long)a0 * MNBR + elo];
        const int j1 = idxp[(long)a1 * MNBR + elo];
        const short* xj0 = xbS + (long)j0 * FDIM + hi * 8;
        const short* xj1 = xbS + (long)j1 * FDIM + hi * 8;
        const short* nb0 = nbS + ((long)a0 * MNBR + elo) * KP48;
        const short* nb1 = nbS + ((long)a1 * MNBR + elo) * KP48;
        bf16x8 A00 = *(const bf16x8*)(xj0);
        bf16x8 A01 = *(const bf16x8*)(xj0 + 32);
        bf16x8 A02 = *(const bf16x8*)(nb0 + hi * 8);
        bf16x8 n03 = *(const bf16x8*)(nb0 + off1);
        bf16x8 A03 = (hi < 2) ? n03 : zz;            // k=48..63 are zero
        bf16x8 A10 = *(const bf16x8*)(xj1);
        bf16x8 A11 = *(const bf16x8*)(xj1 + 32);
        bf16x8 A12 = *(const bf16x8*)(nb1 + hi * 8);
        bf16x8 n13 = *(const bf16x8*)(nb1 + off1);
        bf16x8 A13 = (hi < 2) ? n13 : zz;

        if (APPLY == 0) {
#pragma unroll 2
            for (int P = 0; P < 8; ++P) {
                const short* bp = bb + P * 2048 + l * 8;
                bf16x8 B0 = *(const bf16x8*)(bp);
                bf16x8 B1 = *(const bf16x8*)(bp + 512);
                bf16x8 B2 = *(const bf16x8*)(bp + 1024);
                bf16x8 B3 = *(const bf16x8*)(bp + 1536);
                float a0v = bf2f((unsigned short)aSS[(long)a0 * C2 + P * 16 + lo]);
                float a1v = bf2f((unsigned short)aSS[(long)a1 * C2 + P * 16 + lo]);
                f32x4 z0 = {0.f, 0.f, 0.f, 0.f}, z1 = {0.f, 0.f, 0.f, 0.f};
                z0 = __builtin_amdgcn_mfma_f32_16x16x32_bf16(A00, B0, z0, 0, 0, 0);
                z1 = __builtin_amdgcn_mfma_f32_16x16x32_bf16(A10, B0, z1, 0, 0, 0);
                z0 = __builtin_amdgcn_mfma_f32_16x16x32_bf16(A01, B1, z0, 0, 0, 0);
                z1 = __builtin_amdgcn_mfma_f32_16x16x32_bf16(A11, B1, z1, 0, 0, 0);
                z0 = __builtin_amdgcn_mfma_f32_16x16x32_bf16(A02, B2, z0, 0, 0, 0);
                z1 = __builtin_amdgcn_mfma_f32_16x16x32_bf16(A12, B2, z1, 0, 0, 0);
                z0 = __builtin_amdgcn_mfma_f32_16x16x32_bf16(A03, B3, z0, 0, 0, 0);
                z1 = __builtin_amdgcn_mfma_f32_16x16x32_bf16(A13, B3, z1, 0, 0, 0);
#pragma unroll
                for (int g = 0; g < 2; ++g) {
                    f32x4 z = g ? z1 : z0;
                    float av = g ? a1v : a0v;
                    float sz = z[0] + z[1] + z[2] + z[3];
                    float szz = z[0] * z[0] + z[1] * z[1] + z[2] * z[2] + z[3] * z[3];
                    float s1 = sz + 4.f * av;
                    float s2 = szz + 2.f * av * sz + 4.f * av * av;
                    if (hi == 3) { s1 = 0.f; s2 = 0.f; }   // mask pad rows
                    s1 += __shfl_xor(s1, 16); s2 += __shfl_xor(s2, 16);
                    s1 += __shfl_xor(s1, 32); s2 += __shfl_xor(s2, 32);
                    if (hi == 0) {
                        atomicAdd(&bn_s[P * 16 + lo], s1);
                        atomicAdd(&bn_s[128 + P * 16 + lo], s2);
                    }
                }
            }
        } else {
#pragma unroll 1
            for (int P = 0; P < 4; ++P) {
                const short* bpf = bb + P * 2048 + l * 8;
                const short* bpc = bb + (P + 4) * 2048 + l * 8;
                bf16x8 Bf0 = *(const bf16x8*)(bpf);
                bf16x8 Bf1 = *(const bf16x8*)(bpf + 512);
                bf16x8 Bf2 = *(const bf16x8*)(bpf + 1024);
                bf16x8 Bf3 = *(const bf16x8*)(bpf + 1536);
                bf16x8 Bc0 = *(const bf16x8*)(bpc);
                bf16x8 Bc1 = *(const bf16x8*)(bpc + 512);
                bf16x8 Bc2 = *(const bf16x8*)(bpc + 1024);
                bf16x8 Bc3 = *(const bf16x8*)(bpc + 1536);
                const int c = P * 16 + lo;
                const float s_f = sc_s[c], h_f = sh_s[c];
                const float s_c = sc_s[64 + c], h_c = sh_s[64 + c];
                float hv0f = bf2f((unsigned short)aSS[(long)a0 * C2 + c]) * s_f + h_f;
                float hv0c = bf2f((unsigned short)aSS[(long)a0 * C2 + 64 + c]) * s_c + h_c;
                float hv1f = bf2f((unsigned short)aSS[(long)a1 * C2 + c]) * s_f + h_f;
                float hv1c = bf2f((unsigned short)aSS[(long)a1 * C2 + 64 + c]) * s_c + h_c;
                f32x4 zf0 = {0.f, 0.f, 0.f, 0.f}, zc0 = {0.f, 0.f, 0.f, 0.f};
                f32x4 zf1 = {0.f, 0.f, 0.f, 0.f}, zc1 = {0.f, 0.f, 0.f, 0.f};
                zf0 = __builtin_amdgcn_mfma_f32_16x16x32_bf16(A00, Bf0, zf0, 0, 0, 0);
                zc0 = __builtin_amdgcn_mfma_f32_16x16x32_bf16(A00, Bc0, zc0, 0, 0, 0);
                zf1 = __builtin_amdgcn_mfma_f32_16x16x32_bf16(A10, Bf0, zf1, 0, 0, 0);
                zc1 = __builtin_amdgcn_mfma_f32_16x16x32_bf16(A10, Bc0, zc1, 0, 0, 0);
                zf0 = __builtin_amdgcn_mfma_f32_16x16x32_bf16(A01, Bf1, zf0, 0, 0, 0);
                zc0 = __builtin_amdgcn_mfma_f32_16x16x32_bf16(A01, Bc1, zc0, 0, 0, 0);
                zf1 = __builtin_amdgcn_mfma_f32_16x16x32_bf16(A11, Bf1, zf1, 0, 0, 0);
                zc1 = __builtin_amdgcn_mfma_f32_16x16x32_bf16(A11, Bc1, zc1, 0, 0, 0);
                zf0 = __builtin_amdgcn_mfma_f32_16x16x32_bf16(A02, Bf2, zf0, 0, 0, 0);
                zc0 = __builtin_amdgcn_mfma_f32_16x16x32_bf16(A02, Bc2, zc0, 0, 0, 0);
                zf1 = __builtin_amdgcn_mfma_f32_16x16x32_bf16(A12, Bf2, zf1, 0, 0, 0);
                zc1 = __builtin_amdgcn_mfma_f32_16x16x32_bf16(A12, Bc2, zc1, 0, 0, 0);
                zf0 = __builtin_amdgcn_mfma_f32_16x16x32_bf16(A03, Bf3, zf0, 0, 0, 0);
                zc0 = __builtin_amdgcn_mfma_f32_16x16x32_bf16(A03, Bc3, zc0, 0, 0, 0);
                zf1 = __builtin_amdgcn_mfma_f32_16x16x32_bf16(A13, Bf3, zf1, 0, 0, 0);
                zc1 = __builtin_amdgcn_mfma_f32_16x16x32_bf16(A13, Bc3, zc1, 0, 0, 0);
#pragma unroll
                for (int g = 0; g < 2; ++g) {
                    f32x4 zf = g ? zf1 : zf0;
                    f32x4 zc = g ? zc1 : zc0;
                    float hvf = g ? hv1f : hv0f;
                    float hvc = g ? hv1c : hv0c;
                    float pvsum = 0.f;
#pragma unroll
                    for (int qq = 0; qq < 4; ++qq) {
                        float zfh = zf[qq] * s_f + hvf;
                        float zch = zc[qq] * s_c + hvc;
                        float filt = 1.f / (1.f + __expf(-zfh));
                        pvsum += filt * softplus_f(zch);
                    }
                    if (hi == 3) pvsum = 0.f;   // mask pad rows
                    pvsum += __shfl_xor(pvsum, 16);
                    pvsum += __shfl_xor(pvsum, 32);
                    if (hi == 0) {
                        sout[(long)(g ? a1 : a0) * FDIM + c] = pvsum;
                        atomicAdd(&bn_s[c], pvsum);
                        atomicAdd(&bn_s[64 + c], pvsum * pvsum);
                    }
                }
            }
        }
    }

    __syncthreads();
    if (APPLY == 0) {
        atomicAdd(&bn1_slots[(blockIdx.x & 63) * 256 + t], bn_s[t]);
    } else {
        if (t < 128)
            atomicAdd(&bn2_slots[(blockIdx.x & 63) * 128 + t], bn_s[t]);
    }
}

// reduce 64 slots -> scale/shift; zero slots for next layer.
// Linear bias is a no-op under training-mode BN -> no bias anywhere.
__global__ void k_bnfin(float* __restrict__ slots, const float* __restrict__ gamma,
                        const float* __restrict__ beta,
                        float* __restrict__ scale, float* __restrict__ shift,
                        float inv_cnt, int nc) {
    int c = threadIdx.x;
    if (c >= nc) return;
    float s1 = 0.f, s2 = 0.f;
    for (int s = 0; s < 64; ++s) {
        s1 += slots[s * 2 * nc + c];
        s2 += slots[s * 2 * nc + nc + c];
    }
    for (int s = 0; s < 64; ++s) {
        slots[s * 2 * nc + c] = 0.f;
        slots[s * 2 * nc + nc + c] = 0.f;
    }
    float mu = s1 * inv_cnt;
    float var = fmaxf(s2 * inv_cnt - mu * mu, 0.f);
    float sc = gamma[c] * rsqrtf(var + EPSBN);
    scale[c] = sc;
    shift[c] = beta[c] - mu * sc;
}

// x = softplus(x + bn2(s)); also refresh xb
__global__ void k_x(float* __restrict__ x, __hip_bfloat16* __restrict__ xb,
                    const float* __restrict__ s,
                    const float* __restrict__ scale2, const float* __restrict__ shift2) {
    long i = (long)blockIdx.x * 256 + threadIdx.x;
    if (i >= (long)NATOM * FDIM) return;
    int c = (int)(i & 63);
    float v = softplus_f(x[i] + s[i] * scale2[c] + shift2[c]);
    x[i] = v;
    xb[i] = __float2bfloat16(v);
}

__global__ void k_pool(const float* __restrict__ x, const int* __restrict__ seg,
                       float* __restrict__ cry, float* __restrict__ cnt) {
    long i = (long)blockIdx.x * 256 + threadIdx.x;
    if (i >= (long)NATOM * FDIM) return;
    int n = (int)(i >> 6), c = (int)(i & 63);
    int cr = seg[n];
    atomicAdd(&cry[(long)cr * FDIM + c], x[i]);
    if (c == 0) atomicAdd(&cnt[cr], 1.f);
}

__global__ __launch_bounds__(256)
void k_head(const float* __restrict__ cry, const float* __restrict__ cnt,
            const float* __restrict__ fw, const float* __restrict__ fb,
            const float* __restrict__ hw, const float* __restrict__ hb,
            const float* __restrict__ ow, const float* __restrict__ ob,
            float* __restrict__ out) {
    __shared__ float cs[64], h1[128], red[256];
    int t = threadIdx.x, cr = blockIdx.x;
    if (t < 64) cs[t] = cry[(long)cr * 64 + t] / fmaxf(cnt[cr], 1.f);
    __syncthreads();
    if (t < 128) {
        float a = fb[t];
        for (int k = 0; k < 64; ++k) a += cs[k] * fw[k * 128 + t];
        h1[t] = fmaxf(a, 0.f);
    }
    __syncthreads();
    float a = hb[t];
    for (int k = 0; k < 128; ++k) a += h1[k] * hw[k * 256 + t];
    red[t] = a * ow[t];
    __syncthreads();
    for (int off = 128; off > 0; off >>= 1) {
        if (t < off) red[t] += red[t + off];
        __syncthreads();
    }
    if (t == 0) out[cr] = red[0] + ob[0];
}

extern "C" void kernel_launch(void* const* d_in, const int* in_sizes, int n_in,
                              void* d_out, int out_size, void* d_ws, size_t ws_size,
                              hipStream_t stream) {
    const float* atom_fea = (const float*)d_in[0];
    const float* nbr_fea  = (const float*)d_in[1];
    const int*   nbr_idx  = (const int*)d_in[2];
    const int*   seg      = (const int*)d_in[3];
    const float* emb_w    = (const float*)d_in[4];
    const float* emb_b    = (const float*)d_in[5];
    const float* conv_w   = (const float*)d_in[6];
    const float* bn1_g    = (const float*)d_in[8];
    const float* bn1_b    = (const float*)d_in[9];
    const float* bn2_g    = (const float*)d_in[10];
    const float* bn2_b    = (const float*)d_in[11];
    const float* fc_w     = (const float*)d_in[12];
    const float* fc_b     = (const float*)d_in[13];
    const float* head_w   = (const float*)d_in[14];
    const float* head_b   = (const float*)d_in[15];
    const float* out_w    = (const float*)d_in[16];
    const float* out_b    = (const float*)d_in[17];
    float* out = (float*)d_out;

    float* ws = (float*)d_ws;
    float* x = ws + X_OFF;
    __hip_bfloat16* xb     = (__hip_bfloat16*)(ws + XB_OFF);
    float* s = ws + S_OFF;
    __hip_bfloat16* nbrb   = (__hip_bfloat16*)(ws + NBRB_OFF);
    __hip_bfloat16* aS     = (__hip_bfloat16*)(ws + AS_OFF);
    __hip_bfloat16* ballf  = (__hip_bfloat16*)(ws + BALL_OFF);
    __hip_bfloat16* ballfS = (__hip_bfloat16*)(ws + BALLS_OFF);
    float* bn1s = ws + BN1S_OFF;
    float* bn2s = ws + BN2S_OFF;
    float* sc1 = ws + SC1_OFF;
    float* sh1 = ws + SH1_OFF;
    float* sc2 = ws + SC2_OFF;
    float* sh2 = ws + SH2_OFF;
    float* cry = ws + CRY_OFF;
    float* cnt = ws + CNT_OFF;

    k_zero<<<(int)((ZERO_CNT + 255) / 256), 256, 0, stream>>>(ws + ZERO_OFF, ZERO_CNT);
    k_nbrcvt<<<(int)(((long)NEDGE * 6 + 255) / 256), 256, 0, stream>>>(nbr_fea, nbrb);
    k_embed<<<NATOM / 16, 256, 0, stream>>>(atom_fea, emb_w, emb_b, x, xb);

    for (int i = 0; i < 3; ++i) {
        const float* cw = conv_w + (long)i * 169 * C2;
        k_bcvt<<<96, 256, 0, stream>>>(cw, ballf, ballfS);
        k_lin<<<1563, 256, 0, stream>>>(xb, ballfS, aS);
        k_edge<0><<<NATOM / 16, 256, 0, stream>>>(xb, nbrb, ballf, aS, nbr_idx,
                                                  nullptr, nullptr, bn1s, nullptr, nullptr);
        k_bnfin<<<1, 128, 0, stream>>>(bn1s, bn1_g + i * C2, bn1_b + i * C2,
                                       sc1, sh1, 1.f / 1200000.f, 128);
        k_edge<1><<<NATOM / 16, 256, 0, stream>>>(xb, nbrb, ballf, aS, nbr_idx,
                                                  sc1, sh1, nullptr, s, bn2s);
        k_bnfin<<<1, 64, 0, stream>>>(bn2s, bn2_g + i * 64, bn2_b + i * 64,
                                      sc2, sh2, 1e-5f, 64);
        k_x<<<(NATOM * FDIM) / 256, 256, 0, stream>>>(x, xb, s, sc2, sh2);
    }

    k_pool<<<(NATOM * FDIM) / 256, 256, 0, stream>>>(x, seg, cry, cnt);
    k_head<<<2000, 256, 0, stream>>>(cry, cnt, fc_w, fc_b, head_w, head_b, out_w, out_b, out);
}

// Round 14
// 1377.945 us; speedup vs baseline: 1.2330x; 1.2330x over previous
//
#include <hip/hip_runtime.h>
#include <hip/hip_bf16.h>

#define NATOM 100000
#define MNBR  12
#define FDIM  64
#define BDIM  41
#define C2    128
#define EPSBN 1e-5f
#define NEDGE (NATOM * MNBR)   // 1,200,000
#define KP48  48               // nbr packed width (41 real + 7 zero), 96B rows
#define NFRAG  16384           // edge B frag-linear: 8T * 4s * 64l * 8e (rows 64..168)
#define NFRAGS 8192            // self B frag-linear: 8T * 2s * 64l * 8e (rows 0..63)

typedef __attribute__((ext_vector_type(8))) short bf16x8;
typedef __attribute__((ext_vector_type(4))) unsigned short u16x4;
typedef __attribute__((ext_vector_type(4))) float f32x4;

// ---- ws layout (float units) ----
#define X_OFF    0L            // x: N*64 f32 (master)
#define XB_OFF   6400000L      // xb: N*64 bf16
#define S_OFF    9600000L      // nbr_sumed: N*64 f32
#define NBRB_OFF 16000000L     // nbr bf16 packed 48-wide: 1.2M*48 bf16 (28.8M floats)
#define AS_OFF   54400000L     // a = x@W_self: N*128 bf16 (6.4M floats)
#define BALL_OFF 60800000L     // edge B frag bf16: 16384 elems (8192 floats)
#define BALLS_OFF 60808192L    // self B frag bf16: 8192 elems (4096 floats)
#define BN1S_OFF 60812288L     // 64 slots * 256
#define BN2S_OFF 60828672L     // 64 slots * 128
#define SC1_OFF  60836864L
#define SH1_OFF  60836992L
#define SC2_OFF  60837120L
#define SH2_OFF  60837184L
#define CRY_OFF  60837248L     // 2000*64
#define CNT_OFF  60965248L     // 2000
#define ZB_OFF   60967296L     // z bf16: N*1536 bf16 (76.8M floats) -- fused path only
#define WS_NEED_FUSED ((ZB_OFF + 76800000L) * 4L)   // 551,069,184 bytes
#define ZERO_OFF BN1S_OFF
#define ZERO_CNT 154960L

__device__ __forceinline__ float bf2f(unsigned short u) {
    return __uint_as_float(((unsigned)u) << 16);
}
__device__ __forceinline__ unsigned short f2bf(float f) {
    __hip_bfloat16 h = __float2bfloat16(f);
    return *(unsigned short*)&h;
}
__device__ __forceinline__ float softplus_f(float v) {
    return fmaxf(v, 0.f) + __logf(1.f + __expf(-fabsf(v)));
}

__global__ void k_zero(float* __restrict__ p, long cnt) {
    long i = (long)blockIdx.x * 256 + threadIdx.x;
    if (i < cnt) p[i] = 0.f;
}

// nbr_fea f32 [1.2M][41] -> bf16 [1.2M][48] zero-padded; short8-vectorized writes
__global__ void k_nbrcvt(const float* __restrict__ nbr, __hip_bfloat16* __restrict__ outb) {
    long i = (long)blockIdx.x * 256 + threadIdx.x;   // one 8-elem chunk each
    if (i >= (long)NEDGE * 6) return;
    long e = i / 6;
    int c = (int)(i - e * 6);
    const float* src = nbr + e * BDIM + c * 8;
    bf16x8 v;
#pragma unroll
    for (int j = 0; j < 8; ++j) {
        int k = c * 8 + j;
        float f = (k < BDIM) ? src[j] : 0.f;
        v[j] = (short)f2bf(f);
    }
    *(bf16x8*)((short*)outb + e * KP48 + c * 8) = v;
}

// Fragment-linear B for both GEMMs.
__global__ void k_bcvt(const float* __restrict__ cw, __hip_bfloat16* __restrict__ ballf,
                       __hip_bfloat16* __restrict__ ballfS) {
    int i = blockIdx.x * 256 + threadIdx.x;
    if (i < NFRAG) {
        int T = i / 2048, r = i - T * 2048;
        int lidx = (r >> 3) & 63, e = i & 7;
        int s4 = r >> 9;
        int lo = lidx & 15, hi = lidx >> 4;
        int krow = 64 + s4 * 32 + hi * 8 + e;
        float v = (krow < 169) ? cw[krow * C2 + T * 16 + lo] : 0.f;
        ballf[i] = __float2bfloat16(v);
    } else if (i < NFRAG + NFRAGS) {
        int i2 = i - NFRAG;
        int T = i2 / 1024, r = i2 - T * 1024;
        int lidx = (r >> 3) & 63, e = i2 & 7;
        int s = r >> 9;
        int lo = lidx & 15, hi = lidx >> 4;
        int krow = s * 32 + hi * 8 + e;   // 0..63
        ballfS[i2] = __float2bfloat16(cw[krow * C2 + T * 16 + lo]);
    }
}

__global__ __launch_bounds__(256)
void k_embed(const float* __restrict__ af, const float* __restrict__ ew,
             const float* __restrict__ eb, float* __restrict__ x,
             __hip_bfloat16* __restrict__ xb) {
    int t = threadIdx.x;
    int c = t & 63, ag = t >> 6;
    long n0 = (long)blockIdx.x * 16 + ag * 4;
    float acc[4] = {0.f, 0.f, 0.f, 0.f};
    for (int k4 = 0; k4 < 23; ++k4) {
        float w0 = ew[(4 * k4 + 0) * FDIM + c];
        float w1 = ew[(4 * k4 + 1) * FDIM + c];
        float w2 = ew[(4 * k4 + 2) * FDIM + c];
        float w3 = ew[(4 * k4 + 3) * FDIM + c];
#pragma unroll
        for (int a = 0; a < 4; ++a) {
            const float4* ar = (const float4*)(af + (n0 + a) * 92);
            float4 v = ar[k4];
            acc[a] += v.x * w0 + v.y * w1 + v.z * w2 + v.w * w3;
        }
    }
    float b = eb[c];
#pragma unroll
    for (int a = 0; a < 4; ++a) {
        float v = acc[a] + b;
        x[(n0 + a) * FDIM + c] = v;
        xb[(n0 + a) * FDIM + c] = __float2bfloat16(v);
    }
}

// aS = xb @ W_self via MFMA: one 16-atom tile per wave (A rows = atoms).
__global__ __launch_bounds__(256, 8)
void k_lin(const __hip_bfloat16* __restrict__ xb, const __hip_bfloat16* __restrict__ ballfS,
           __hip_bfloat16* __restrict__ aS) {
    int t = threadIdx.x, w = t >> 6, l = t & 63;
    int lo = l & 15, hi = l >> 4;
    long atom0 = ((long)blockIdx.x * 4 + w) * 16;
    if (atom0 >= NATOM) return;
    const short* xs = (const short*)xb + (atom0 + lo) * FDIM + hi * 8;
    bf16x8 A0 = *(const bf16x8*)(xs);
    bf16x8 A1 = *(const bf16x8*)(xs + 32);
    const short* bS = (const short*)ballfS;
#pragma unroll
    for (int T = 0; T < 8; ++T) {
        bf16x8 B0 = *(const bf16x8*)(bS + T * 1024 + l * 8);
        bf16x8 B1 = *(const bf16x8*)(bS + T * 1024 + 512 + l * 8);
        f32x4 z = {0.f, 0.f, 0.f, 0.f};
        z = __builtin_amdgcn_mfma_f32_16x16x32_bf16(A0, B0, z, 0, 0, 0);
        z = __builtin_amdgcn_mfma_f32_16x16x32_bf16(A1, B1, z, 0, 0, 0);
#pragma unroll
        for (int qq = 0; qq < 4; ++qq)
            aS[(atom0 + hi * 4 + qq) * C2 + T * 16 + lo] = __float2bfloat16(z[qq]);
    }
}

// Edge kernel (r11 structure): one atom per 16x16 MFMA tile (12 real rows + 4
// pads, masked), K=128 ([x[j] | nbr48]); self term a folded IN-REGISTER into z.
// APPLY=0: BN1 stats; if ZSTORE, also store z' (z+a) bf16 in fragment-native
// layout zb[atom*1536 + T*192 + hi*64 + lo*4], rows 0..11 only.
// APPLY=1 (fallback only): recompute GEMM + BN1 apply + activation + m-sum.
template <int APPLY, int ZSTORE>
__global__ __launch_bounds__(256, 4)
void k_edge(const __hip_bfloat16* __restrict__ xb,
            const __hip_bfloat16* __restrict__ nbrb,
            const __hip_bfloat16* __restrict__ ballf,
            const __hip_bfloat16* __restrict__ aS,
            const int* __restrict__ idxp,
            const float* __restrict__ sc1, const float* __restrict__ sh1,
            float* __restrict__ bn1_slots,
            float* __restrict__ sout, float* __restrict__ bn2_slots,
            __hip_bfloat16* __restrict__ zb) {
    __shared__ float bn_s[256];
    __shared__ float sc_s[128], sh_s[128];

    const int t = threadIdx.x;
    const int w = t >> 6, l = t & 63;
    const int lo = l & 15, hi = l >> 4;
    const bool real = lo < MNBR;
    const int elo = real ? lo : 0;           // clamp pad lanes in-bounds
    const int atom0 = blockIdx.x * 16 + w * 4;
    const short* xbS = (const short*)xb;
    const short* nbS = (const short*)nbrb;
    const short* aSS = (const short*)aS;
    const short* bb  = (const short*)ballf;
    short* zbS = (short*)zb;

    bn_s[t] = 0.f;
    if (APPLY && t < 128) { sc_s[t] = sc1[t]; sh_s[t] = sh1[t]; }
    __syncthreads();

    const bf16x8 zz = {0, 0, 0, 0, 0, 0, 0, 0};
    const int off1 = (hi < 2) ? (32 + hi * 8) : 0;   // slice-1 source (k=32..47) or dummy

#pragma unroll 1
    for (int pr = 0; pr < 2; ++pr) {
        const int a0 = atom0 + pr * 2;
        const int a1 = a0 + 1;
        const int j0 = idxp[(long)a0 * MNBR + elo];
        const int j1 = idxp[(long)a1 * MNBR + elo];
        const short* xj0 = xbS + (long)j0 * FDIM + hi * 8;
        const short* xj1 = xbS + (long)j1 * FDIM + hi * 8;
        const short* nb0 = nbS + ((long)a0 * MNBR + elo) * KP48;
        const short* nb1 = nbS + ((long)a1 * MNBR + elo) * KP48;
        bf16x8 A00 = *(const bf16x8*)(xj0);
        bf16x8 A01 = *(const bf16x8*)(xj0 + 32);
        bf16x8 A02 = *(const bf16x8*)(nb0 + hi * 8);
        bf16x8 n03 = *(const bf16x8*)(nb0 + off1);
        bf16x8 A03 = (hi < 2) ? n03 : zz;            // k=48..63 are zero
        bf16x8 A10 = *(const bf16x8*)(xj1);
        bf16x8 A11 = *(const bf16x8*)(xj1 + 32);
        bf16x8 A12 = *(const bf16x8*)(nb1 + hi * 8);
        bf16x8 n13 = *(const bf16x8*)(nb1 + off1);
        bf16x8 A13 = (hi < 2) ? n13 : zz;

        if (APPLY == 0) {
#pragma unroll 2
            for (int P = 0; P < 8; ++P) {
                const short* bp = bb + P * 2048 + l * 8;
                bf16x8 B0 = *(const bf16x8*)(bp);
                bf16x8 B1 = *(const bf16x8*)(bp + 512);
                bf16x8 B2 = *(const bf16x8*)(bp + 1024);
                bf16x8 B3 = *(const bf16x8*)(bp + 1536);
                float a0v = bf2f((unsigned short)aSS[(long)a0 * C2 + P * 16 + lo]);
                float a1v = bf2f((unsigned short)aSS[(long)a1 * C2 + P * 16 + lo]);
                f32x4 z0 = {0.f, 0.f, 0.f, 0.f}, z1 = {0.f, 0.f, 0.f, 0.f};
                z0 = __builtin_amdgcn_mfma_f32_16x16x32_bf16(A00, B0, z0, 0, 0, 0);
                z1 = __builtin_amdgcn_mfma_f32_16x16x32_bf16(A10, B0, z1, 0, 0, 0);
                z0 = __builtin_amdgcn_mfma_f32_16x16x32_bf16(A01, B1, z0, 0, 0, 0);
                z1 = __builtin_amdgcn_mfma_f32_16x16x32_bf16(A11, B1, z1, 0, 0, 0);
                z0 = __builtin_amdgcn_mfma_f32_16x16x32_bf16(A02, B2, z0, 0, 0, 0);
                z1 = __builtin_amdgcn_mfma_f32_16x16x32_bf16(A12, B2, z1, 0, 0, 0);
                z0 = __builtin_amdgcn_mfma_f32_16x16x32_bf16(A03, B3, z0, 0, 0, 0);
                z1 = __builtin_amdgcn_mfma_f32_16x16x32_bf16(A13, B3, z1, 0, 0, 0);
#pragma unroll
                for (int g = 0; g < 2; ++g) {
                    f32x4 z = g ? z1 : z0;
                    float av = g ? a1v : a0v;
                    // fold self term into z' per element
                    float zp0 = z[0] + av, zp1 = z[1] + av, zp2 = z[2] + av, zp3 = z[3] + av;
                    if (ZSTORE && hi < 3) {
                        u16x4 pk = {f2bf(zp0), f2bf(zp1), f2bf(zp2), f2bf(zp3)};
                        *(u16x4*)&zbS[(long)(g ? a1 : a0) * 1536 + P * 192 + hi * 64 + lo * 4] = pk;
                    }
                    float s1 = zp0 + zp1 + zp2 + zp3;
                    float s2 = zp0 * zp0 + zp1 * zp1 + zp2 * zp2 + zp3 * zp3;
                    if (hi == 3) { s1 = 0.f; s2 = 0.f; }   // mask pad rows
                    s1 += __shfl_xor(s1, 16); s2 += __shfl_xor(s2, 16);
                    s1 += __shfl_xor(s1, 32); s2 += __shfl_xor(s2, 32);
                    if (hi == 0) {
                        atomicAdd(&bn_s[P * 16 + lo], s1);
                        atomicAdd(&bn_s[128 + P * 16 + lo], s2);
                    }
                }
            }
        } else {
#pragma unroll 1
            for (int P = 0; P < 4; ++P) {
                const short* bpf = bb + P * 2048 + l * 8;
                const short* bpc = bb + (P + 4) * 2048 + l * 8;
                bf16x8 Bf0 = *(const bf16x8*)(bpf);
                bf16x8 Bf1 = *(const bf16x8*)(bpf + 512);
                bf16x8 Bf2 = *(const bf16x8*)(bpf + 1024);
                bf16x8 Bf3 = *(const bf16x8*)(bpf + 1536);
                bf16x8 Bc0 = *(const bf16x8*)(bpc);
                bf16x8 Bc1 = *(const bf16x8*)(bpc + 512);
                bf16x8 Bc2 = *(const bf16x8*)(bpc + 1024);
                bf16x8 Bc3 = *(const bf16x8*)(bpc + 1536);
                const int c = P * 16 + lo;
                const float s_f = sc_s[c], h_f = sh_s[c];
                const float s_c = sc_s[64 + c], h_c = sh_s[64 + c];
                float hv0f = bf2f((unsigned short)aSS[(long)a0 * C2 + c]) * s_f + h_f;
                float hv0c = bf2f((unsigned short)aSS[(long)a0 * C2 + 64 + c]) * s_c + h_c;
                float hv1f = bf2f((unsigned short)aSS[(long)a1 * C2 + c]) * s_f + h_f;
                float hv1c = bf2f((unsigned short)aSS[(long)a1 * C2 + 64 + c]) * s_c + h_c;
                f32x4 zf0 = {0.f, 0.f, 0.f, 0.f}, zc0 = {0.f, 0.f, 0.f, 0.f};
                f32x4 zf1 = {0.f, 0.f, 0.f, 0.f}, zc1 = {0.f, 0.f, 0.f, 0.f};
                zf0 = __builtin_amdgcn_mfma_f32_16x16x32_bf16(A00, Bf0, zf0, 0, 0, 0);
                zc0 = __builtin_amdgcn_mfma_f32_16x16x32_bf16(A00, Bc0, zc0, 0, 0, 0);
                zf1 = __builtin_amdgcn_mfma_f32_16x16x32_bf16(A10, Bf0, zf1, 0, 0, 0);
                zc1 = __builtin_amdgcn_mfma_f32_16x16x32_bf16(A10, Bc0, zc1, 0, 0, 0);
                zf0 = __builtin_amdgcn_mfma_f32_16x16x32_bf16(A01, Bf1, zf0, 0, 0, 0);
                zc0 = __builtin_amdgcn_mfma_f32_16x16x32_bf16(A01, Bc1, zc0, 0, 0, 0);
                zf1 = __builtin_amdgcn_mfma_f32_16x16x32_bf16(A11, Bf1, zf1, 0, 0, 0);
                zc1 = __builtin_amdgcn_mfma_f32_16x16x32_bf16(A11, Bc1, zc1, 0, 0, 0);
                zf0 = __builtin_amdgcn_mfma_f32_16x16x32_bf16(A02, Bf2, zf0, 0, 0, 0);
                zc0 = __builtin_amdgcn_mfma_f32_16x16x32_bf16(A02, Bc2, zc0, 0, 0, 0);
                zf1 = __builtin_amdgcn_mfma_f32_16x16x32_bf16(A12, Bf2, zf1, 0, 0, 0);
                zc1 = __builtin_amdgcn_mfma_f32_16x16x32_bf16(A12, Bc2, zc1, 0, 0, 0);
                zf0 = __builtin_amdgcn_mfma_f32_16x16x32_bf16(A03, Bf3, zf0, 0, 0, 0);
                zc0 = __builtin_amdgcn_mfma_f32_16x16x32_bf16(A03, Bc3, zc0, 0, 0, 0);
                zf1 = __builtin_amdgcn_mfma_f32_16x16x32_bf16(A13, Bf3, zf1, 0, 0, 0);
                zc1 = __builtin_amdgcn_mfma_f32_16x16x32_bf16(A13, Bc3, zc1, 0, 0, 0);
#pragma unroll
                for (int g = 0; g < 2; ++g) {
                    f32x4 zf = g ? zf1 : zf0;
                    f32x4 zc = g ? zc1 : zc0;
                    float hvf = g ? hv1f : hv0f;
                    float hvc = g ? hv1c : hv0c;
                    float pvsum = 0.f;
#pragma unroll
                    for (int qq = 0; qq < 4; ++qq) {
                        float zfh = zf[qq] * s_f + hvf;
                        float zch = zc[qq] * s_c + hvc;
                        float filt = 1.f / (1.f + __expf(-zfh));
                        pvsum += filt * softplus_f(zch);
                    }
                    if (hi == 3) pvsum = 0.f;   // mask pad rows
                    pvsum += __shfl_xor(pvsum, 16);
                    pvsum += __shfl_xor(pvsum, 32);
                    if (hi == 0) {
                        sout[(long)(g ? a1 : a0) * FDIM + c] = pvsum;
                        atomicAdd(&bn_s[c], pvsum);
                        atomicAdd(&bn_s[64 + c], pvsum * pvsum);
                    }
                }
            }
        }
    }

    __syncthreads();
    if (APPLY == 0) {
        atomicAdd(&bn1_slots[(blockIdx.x & 63) * 256 + t], bn_s[t]);
    } else {
        if (t < 128)
            atomicAdd(&bn2_slots[(blockIdx.x & 63) * 128 + t], bn_s[t]);
    }
}

// Streaming apply: read stored z' bf16 (fragment-native layout), BN1 apply +
// sigmoid*softplus + m-sum -> sout + BN2 stats. No gather, no B, no MFMA.
__global__ __launch_bounds__(256, 8)
void k_zapply(const __hip_bfloat16* __restrict__ zb,
              const float* __restrict__ sc1, const float* __restrict__ sh1,
              float* __restrict__ sout, float* __restrict__ bn2_slots) {
    __shared__ float bn_s[128];
    __shared__ float sc_s[128], sh_s[128];
    const int t = threadIdx.x;
    const int w = t >> 6, l = t & 63;
    const int lo = l & 15, hi = l >> 4;
    if (t < 128) { bn_s[t] = 0.f; sc_s[t] = sc1[t]; sh_s[t] = sh1[t]; }
    __syncthreads();

    const int atom0 = blockIdx.x * 16 + w * 4;
    const short* zs = (const short*)zb;
    const int hiC = (hi < 3) ? hi : 0;   // pad lanes read row 0 (masked)

#pragma unroll
    for (int a = 0; a < 4; ++a) {
        const long base = (long)(atom0 + a) * 1536 + hiC * 64 + lo * 4;
#pragma unroll
        for (int P = 0; P < 4; ++P) {
            u16x4 zf = *(const u16x4*)&zs[base + P * 192];
            u16x4 zc = *(const u16x4*)&zs[base + (P + 4) * 192];
            const int c = P * 16 + lo;
            const float s_f = sc_s[c], h_f = sh_s[c];
            const float s_c = sc_s[64 + c], h_c = sh_s[64 + c];
            float pvsum = 0.f;
#pragma unroll
            for (int qq = 0; qq < 4; ++qq) {
                float zfh = bf2f(zf[qq]) * s_f + h_f;
                float zch = bf2f(zc[qq]) * s_c + h_c;
                float filt = 1.f / (1.f + __expf(-zfh));
                pvsum += filt * softplus_f(zch);
            }
            if (hi == 3) pvsum = 0.f;
            pvsum += __shfl_xor(pvsum, 16);
            pvsum += __shfl_xor(pvsum, 32);
            if (hi == 0) {
                sout[(long)(atom0 + a) * FDIM + c] = pvsum;
                atomicAdd(&bn_s[c], pvsum);
                atomicAdd(&bn_s[64 + c], pvsum * pvsum);
            }
        }
    }
    __syncthreads();
    if (t < 128)
        atomicAdd(&bn2_slots[(blockIdx.x & 63) * 128 + t], bn_s[t]);
}

// reduce 64 slots -> scale/shift; zero slots for next layer.
__global__ void k_bnfin(float* __restrict__ slots, const float* __restrict__ gamma,
                        const float* __restrict__ beta,
                        float* __restrict__ scale, float* __restrict__ shift,
                        float inv_cnt, int nc) {
    int c = threadIdx.x;
    if (c >= nc) return;
    float s1 = 0.f, s2 = 0.f;
    for (int s = 0; s < 64; ++s) {
        s1 += slots[s * 2 * nc + c];
        s2 += slots[s * 2 * nc + nc + c];
    }
    for (int s = 0; s < 64; ++s) {
        slots[s * 2 * nc + c] = 0.f;
        slots[s * 2 * nc + nc + c] = 0.f;
    }
    float mu = s1 * inv_cnt;
    float var = fmaxf(s2 * inv_cnt - mu * mu, 0.f);
    float sc = gamma[c] * rsqrtf(var + EPSBN);
    scale[c] = sc;
    shift[c] = beta[c] - mu * sc;
}

// x = softplus(x + bn2(s)); also refresh xb
__global__ void k_x(float* __restrict__ x, __hip_bfloat16* __restrict__ xb,
                    const float* __restrict__ s,
                    const float* __restrict__ scale2, const float* __restrict__ shift2) {
    long i = (long)blockIdx.x * 256 + threadIdx.x;
    if (i >= (long)NATOM * FDIM) return;
    int c = (int)(i & 63);
    float v = softplus_f(x[i] + s[i] * scale2[c] + shift2[c]);
    x[i] = v;
    xb[i] = __float2bfloat16(v);
}

__global__ void k_pool(const float* __restrict__ x, const int* __restrict__ seg,
                       float* __restrict__ cry, float* __restrict__ cnt) {
    long i = (long)blockIdx.x * 256 + threadIdx.x;
    if (i >= (long)NATOM * FDIM) return;
    int n = (int)(i >> 6), c = (int)(i & 63);
    int cr = seg[n];
    atomicAdd(&cry[(long)cr * FDIM + c], x[i]);
    if (c == 0) atomicAdd(&cnt[cr], 1.f);
}

__global__ __launch_bounds__(256)
void k_head(const float* __restrict__ cry, const float* __restrict__ cnt,
            const float* __restrict__ fw, const float* __restrict__ fb,
            const float* __restrict__ hw, const float* __restrict__ hb,
            const float* __restrict__ ow, const float* __restrict__ ob,
            float* __restrict__ out) {
    __shared__ float cs[64], h1[128], red[256];
    int t = threadIdx.x, cr = blockIdx.x;
    if (t < 64) cs[t] = cry[(long)cr * 64 + t] / fmaxf(cnt[cr], 1.f);
    __syncthreads();
    if (t < 128) {
        float a = fb[t];
        for (int k = 0; k < 64; ++k) a += cs[k] * fw[k * 128 + t];
        h1[t] = fmaxf(a, 0.f);
    }
    __syncthreads();
    float a = hb[t];
    for (int k = 0; k < 128; ++k) a += h1[k] * hw[k * 256 + t];
    red[t] = a * ow[t];
    __syncthreads();
    for (int off = 128; off > 0; off >>= 1) {
        if (t < off) red[t] += red[t + off];
        __syncthreads();
    }
    if (t == 0) out[cr] = red[0] + ob[0];
}

extern "C" void kernel_launch(void* const* d_in, const int* in_sizes, int n_in,
                              void* d_out, int out_size, void* d_ws, size_t ws_size,
                              hipStream_t stream) {
    const float* atom_fea = (const float*)d_in[0];
    const float* nbr_fea  = (const float*)d_in[1];
    const int*   nbr_idx  = (const int*)d_in[2];
    const int*   seg      = (const int*)d_in[3];
    const float* emb_w    = (const float*)d_in[4];
    const float* emb_b    = (const float*)d_in[5];
    const float* conv_w   = (const float*)d_in[6];
    const float* bn1_g    = (const float*)d_in[8];
    const float* bn1_b    = (const float*)d_in[9];
    const float* bn2_g    = (const float*)d_in[10];
    const float* bn2_b    = (const float*)d_in[11];
    const float* fc_w     = (const float*)d_in[12];
    const float* fc_b     = (const float*)d_in[13];
    const float* head_w   = (const float*)d_in[14];
    const float* head_b   = (const float*)d_in[15];
    const float* out_w    = (const float*)d_in[16];
    const float* out_b    = (const float*)d_in[17];
    float* out = (float*)d_out;

    float* ws = (float*)d_ws;
    float* x = ws + X_OFF;
    __hip_bfloat16* xb     = (__hip_bfloat16*)(ws + XB_OFF);
    float* s = ws + S_OFF;
    __hip_bfloat16* nbrb   = (__hip_bfloat16*)(ws + NBRB_OFF);
    __hip_bfloat16* aS     = (__hip_bfloat16*)(ws + AS_OFF);
    __hip_bfloat16* ballf  = (__hip_bfloat16*)(ws + BALL_OFF);
    __hip_bfloat16* ballfS = (__hip_bfloat16*)(ws + BALLS_OFF);
    float* bn1s = ws + BN1S_OFF;
    float* bn2s = ws + BN2S_OFF;
    float* sc1 = ws + SC1_OFF;
    float* sh1 = ws + SH1_OFF;
    float* sc2 = ws + SC2_OFF;
    float* sh2 = ws + SH2_OFF;
    float* cry = ws + CRY_OFF;
    float* cnt = ws + CNT_OFF;
    __hip_bfloat16* zb = (__hip_bfloat16*)(ws + ZB_OFF);
    const bool fused = (ws_size >= (size_t)WS_NEED_FUSED);

    k_zero<<<(int)((ZERO_CNT + 255) / 256), 256, 0, stream>>>(ws + ZERO_OFF, ZERO_CNT);
    k_nbrcvt<<<(int)(((long)NEDGE * 6 + 255) / 256), 256, 0, stream>>>(nbr_fea, nbrb);
    k_embed<<<NATOM / 16, 256, 0, stream>>>(atom_fea, emb_w, emb_b, x, xb);

    for (int i = 0; i < 3; ++i) {
        const float* cw = conv_w + (long)i * 169 * C2;
        k_bcvt<<<96, 256, 0, stream>>>(cw, ballf, ballfS);
        k_lin<<<1563, 256, 0, stream>>>(xb, ballfS, aS);
        if (fused) {
            k_edge<0, 1><<<NATOM / 16, 256, 0, stream>>>(xb, nbrb, ballf, aS, nbr_idx,
                                                         nullptr, nullptr, bn1s, nullptr,
                                                         nullptr, zb);
            k_bnfin<<<1, 128, 0, stream>>>(bn1s, bn1_g + i * C2, bn1_b + i * C2,
                                           sc1, sh1, 1.f / 1200000.f, 128);
            k_zapply<<<NATOM / 16, 256, 0, stream>>>(zb, sc1, sh1, s, bn2s);
        } else {
            k_edge<0, 0><<<NATOM / 16, 256, 0, stream>>>(xb, nbrb, ballf, aS, nbr_idx,
                                                         nullptr, nullptr, bn1s, nullptr,
                                                         nullptr, nullptr);
            k_bnfin<<<1, 128, 0, stream>>>(bn1s, bn1_g + i * C2, bn1_b + i * C2,
                                           sc1, sh1, 1.f / 1200000.f, 128);
            k_edge<1, 0><<<NATOM / 16, 256, 0, stream>>>(xb, nbrb, ballf, aS, nbr_idx,
                                                         sc1, sh1, nullptr, s, bn2s, nullptr);
        }
        k_bnfin<<<1, 64, 0, stream>>>(bn2s, bn2_g + i * 64, bn2_b + i * 64,
                                      sc2, sh2, 1e-5f, 64);
        k_x<<<(NATOM * FDIM) / 256, 256, 0, stream>>>(x, xb, s, sc2, sh2);
    }

    k_pool<<<(NATOM * FDIM) / 256, 256, 0, stream>>>(x, seg, cry, cnt);
    k_head<<<2000, 256, 0, stream>>>(cry, cnt, fc_w, fc_b, head_w, head_b, out_w, out_b, out);
}

// Round 15
// 1226.306 us; speedup vs baseline: 1.3855x; 1.1237x over previous
//
#include <hip/hip_runtime.h>
#include <hip/hip_bf16.h>

#define NATOM 100000
#define MNBR  12
#define FDIM  64
#define BDIM  41
#define C2    128
#define EPSBN 1e-5f
#define NEDGE (NATOM * MNBR)   // 1,200,000
#define KP48  48               // nbr packed width (41 real + 7 zero), 96B rows
#define NFRAG  16384           // edge B frag-linear: 8T * 4s * 64l * 8e (rows 64..168)
#define NFRAGS 8192            // self B frag-linear: 8T * 2s * 64l * 8e (rows 0..63)

typedef __attribute__((ext_vector_type(8))) short bf16x8;
typedef __attribute__((ext_vector_type(4))) unsigned short u16x4;
typedef __attribute__((ext_vector_type(4))) float f32x4;

// ---- ws layout (float units) ----
#define X_OFF    0L            // x: N*64 f32 (master)
#define XB_OFF   6400000L      // xb: N*64 bf16
#define S_OFF    9600000L      // nbr_sumed: N*64 f32
#define NBRB_OFF 16000000L     // nbr bf16 packed 48-wide: 1.2M*48 bf16 (28.8M floats)
#define AS_OFF   54400000L     // a = x@W_self: N*128 bf16 (6.4M floats)
#define BALL_OFF 60800000L     // edge B frag bf16: 16384 elems (8192 floats)
#define BALLS_OFF 60808192L    // self B frag bf16: 8192 elems (4096 floats)
#define BN1S_OFF 60812288L     // 64 slots * 256
#define BN2S_OFF 60828672L     // 64 slots * 128
#define SC1_OFF  60836864L
#define SH1_OFF  60836992L
#define SC2_OFF  60837120L
#define SH2_OFF  60837184L
#define CRY_OFF  60837248L     // 2000*64
#define CNT_OFF  60965248L     // 2000
#define ZB_OFF   60967296L     // z bf16: 75000 tiles * 2048 shorts (76.8M floats)
#define WS_NEED_FUSED ((ZB_OFF + 76800000L) * 4L)   // ~551 MB
#define ZERO_OFF BN1S_OFF
#define ZERO_CNT 154960L

__device__ __forceinline__ float bf2f(unsigned short u) {
    return __uint_as_float(((unsigned)u) << 16);
}
__device__ __forceinline__ unsigned short f2bf(float f) {
    __hip_bfloat16 h = __float2bfloat16(f);
    return *(unsigned short*)&h;
}
__device__ __forceinline__ float softplus_f(float v) {
    return fmaxf(v, 0.f) + __logf(1.f + __expf(-fabsf(v)));
}

__global__ void k_zero(float* __restrict__ p, long cnt) {
    long i = (long)blockIdx.x * 256 + threadIdx.x;
    if (i < cnt) p[i] = 0.f;
}

// nbr_fea f32 [1.2M][41] -> bf16 [1.2M][48] zero-padded; short8-vectorized writes
__global__ void k_nbrcvt(const float* __restrict__ nbr, __hip_bfloat16* __restrict__ outb) {
    long i = (long)blockIdx.x * 256 + threadIdx.x;   // one 8-elem chunk each
    if (i >= (long)NEDGE * 6) return;
    long e = i / 6;
    int c = (int)(i - e * 6);
    const float* src = nbr + e * BDIM + c * 8;
    bf16x8 v;
#pragma unroll
    for (int j = 0; j < 8; ++j) {
        int k = c * 8 + j;
        float f = (k < BDIM) ? src[j] : 0.f;
        v[j] = (short)f2bf(f);
    }
    *(bf16x8*)((short*)outb + e * KP48 + c * 8) = v;
}

// Fragment-linear B for both GEMMs.
__global__ void k_bcvt(const float* __restrict__ cw, __hip_bfloat16* __restrict__ ballf,
                       __hip_bfloat16* __restrict__ ballfS) {
    int i = blockIdx.x * 256 + threadIdx.x;
    if (i < NFRAG) {
        int T = i / 2048, r = i - T * 2048;
        int lidx = (r >> 3) & 63, e = i & 7;
        int s4 = r >> 9;
        int lo = lidx & 15, hi = lidx >> 4;
        int krow = 64 + s4 * 32 + hi * 8 + e;
        float v = (krow < 169) ? cw[krow * C2 + T * 16 + lo] : 0.f;
        ballf[i] = __float2bfloat16(v);
    } else if (i < NFRAG + NFRAGS) {
        int i2 = i - NFRAG;
        int T = i2 / 1024, r = i2 - T * 1024;
        int lidx = (r >> 3) & 63, e = i2 & 7;
        int s = r >> 9;
        int lo = lidx & 15, hi = lidx >> 4;
        int krow = s * 32 + hi * 8 + e;   // 0..63
        ballfS[i2] = __float2bfloat16(cw[krow * C2 + T * 16 + lo]);
    }
}

__global__ __launch_bounds__(256)
void k_embed(const float* __restrict__ af, const float* __restrict__ ew,
             const float* __restrict__ eb, float* __restrict__ x,
             __hip_bfloat16* __restrict__ xb) {
    int t = threadIdx.x;
    int c = t & 63, ag = t >> 6;
    long n0 = (long)blockIdx.x * 16 + ag * 4;
    float acc[4] = {0.f, 0.f, 0.f, 0.f};
    for (int k4 = 0; k4 < 23; ++k4) {
        float w0 = ew[(4 * k4 + 0) * FDIM + c];
        float w1 = ew[(4 * k4 + 1) * FDIM + c];
        float w2 = ew[(4 * k4 + 2) * FDIM + c];
        float w3 = ew[(4 * k4 + 3) * FDIM + c];
#pragma unroll
        for (int a = 0; a < 4; ++a) {
            const float4* ar = (const float4*)(af + (n0 + a) * 92);
            float4 v = ar[k4];
            acc[a] += v.x * w0 + v.y * w1 + v.z * w2 + v.w * w3;
        }
    }
    float b = eb[c];
#pragma unroll
    for (int a = 0; a < 4; ++a) {
        float v = acc[a] + b;
        x[(n0 + a) * FDIM + c] = v;
        xb[(n0 + a) * FDIM + c] = __float2bfloat16(v);
    }
}

// aS = xb @ W_self via MFMA: one 16-atom tile per wave (A rows = atoms).
__global__ __launch_bounds__(256, 8)
void k_lin(const __hip_bfloat16* __restrict__ xb, const __hip_bfloat16* __restrict__ ballfS,
           __hip_bfloat16* __restrict__ aS) {
    int t = threadIdx.x, w = t >> 6, l = t & 63;
    int lo = l & 15, hi = l >> 4;
    long atom0 = ((long)blockIdx.x * 4 + w) * 16;
    if (atom0 >= NATOM) return;
    const short* xs = (const short*)xb + (atom0 + lo) * FDIM + hi * 8;
    bf16x8 A0 = *(const bf16x8*)(xs);
    bf16x8 A1 = *(const bf16x8*)(xs + 32);
    const short* bS = (const short*)ballfS;
#pragma unroll
    for (int T = 0; T < 8; ++T) {
        bf16x8 B0 = *(const bf16x8*)(bS + T * 1024 + l * 8);
        bf16x8 B1 = *(const bf16x8*)(bS + T * 1024 + 512 + l * 8);
        f32x4 z = {0.f, 0.f, 0.f, 0.f};
        z = __builtin_amdgcn_mfma_f32_16x16x32_bf16(A0, B0, z, 0, 0, 0);
        z = __builtin_amdgcn_mfma_f32_16x16x32_bf16(A1, B1, z, 0, 0, 0);
#pragma unroll
        for (int qq = 0; qq < 4; ++qq)
            aS[(atom0 + hi * 4 + qq) * C2 + T * 16 + lo] = __float2bfloat16(z[qq]);
    }
}

// Dense stats+store pass: 16-edge tiles (no pads). Per wave: 2 tiles sharing
// every B fragment (B-loads/edge = 1.0, MFMA/edge = 2.0). z' = z + a[n(e)]
// stored bf16 at zb[tile*2048 + col*16 + row]; BN1 column stats via shfl.
__global__ __launch_bounds__(256, 4)
void k_edge_dense(const __hip_bfloat16* __restrict__ xb,
                  const __hip_bfloat16* __restrict__ nbrb,
                  const __hip_bfloat16* __restrict__ ballf,
                  const __hip_bfloat16* __restrict__ aS,
                  const int* __restrict__ idxp,
                  float* __restrict__ bn1_slots,
                  __hip_bfloat16* __restrict__ zb) {
    __shared__ float bn_s[256];
    const int t = threadIdx.x;
    const int w = t >> 6, l = t & 63;
    const int lo = l & 15, hi = l >> 4;
    const short* xbS = (const short*)xb;
    const short* nbS = (const short*)nbrb;
    const short* aSS = (const short*)aS;
    const short* bb  = (const short*)ballf;
    short* zbS = (short*)zb;

    bn_s[t] = 0.f;
    __syncthreads();

    const long tile0 = (long)blockIdx.x * 8 + w * 2;   // tiles tile0, tile0+1
    const bf16x8 zz = {0, 0, 0, 0, 0, 0, 0, 0};
    const int off1 = (hi < 2) ? (32 + hi * 8) : 0;

    bf16x8 A[2][4];
    long ebase[2];
#pragma unroll
    for (int g = 0; g < 2; ++g) {
        const long e0 = (tile0 + g) * 16;
        ebase[g] = e0;
        const int j = idxp[e0 + lo];
        const short* xj = xbS + (long)j * FDIM + hi * 8;
        const short* nb = nbS + (e0 + lo) * KP48;
        A[g][0] = *(const bf16x8*)(xj);
        A[g][1] = *(const bf16x8*)(xj + 32);
        A[g][2] = *(const bf16x8*)(nb + hi * 8);
        bf16x8 n1 = *(const bf16x8*)(nb + off1);
        A[g][3] = (hi < 2) ? n1 : zz;
    }

#pragma unroll 2
    for (int P = 0; P < 8; ++P) {
        const short* bp = bb + P * 2048 + l * 8;
        bf16x8 B0 = *(const bf16x8*)(bp);
        bf16x8 B1 = *(const bf16x8*)(bp + 512);
        bf16x8 B2 = *(const bf16x8*)(bp + 1024);
        bf16x8 B3 = *(const bf16x8*)(bp + 1536);
        f32x4 z0 = {0.f, 0.f, 0.f, 0.f}, z1 = {0.f, 0.f, 0.f, 0.f};
        z0 = __builtin_amdgcn_mfma_f32_16x16x32_bf16(A[0][0], B0, z0, 0, 0, 0);
        z1 = __builtin_amdgcn_mfma_f32_16x16x32_bf16(A[1][0], B0, z1, 0, 0, 0);
        z0 = __builtin_amdgcn_mfma_f32_16x16x32_bf16(A[0][1], B1, z0, 0, 0, 0);
        z1 = __builtin_amdgcn_mfma_f32_16x16x32_bf16(A[1][1], B1, z1, 0, 0, 0);
        z0 = __builtin_amdgcn_mfma_f32_16x16x32_bf16(A[0][2], B2, z0, 0, 0, 0);
        z1 = __builtin_amdgcn_mfma_f32_16x16x32_bf16(A[1][2], B2, z1, 0, 0, 0);
        z0 = __builtin_amdgcn_mfma_f32_16x16x32_bf16(A[0][3], B3, z0, 0, 0, 0);
        z1 = __builtin_amdgcn_mfma_f32_16x16x32_bf16(A[1][3], B3, z1, 0, 0, 0);
#pragma unroll
        for (int g = 0; g < 2; ++g) {
            f32x4 z = g ? z1 : z0;
            float s1 = 0.f, s2 = 0.f;
            u16x4 pk;
#pragma unroll
            for (int qq = 0; qq < 4; ++qq) {
                const int n = (int)((ebase[g] + hi * 4 + qq) / 12);
                float av = bf2f((unsigned short)aSS[(long)n * C2 + P * 16 + lo]);
                float zp = z[qq] + av;
                pk[qq] = f2bf(zp);
                s1 += zp;
                s2 += zp * zp;
            }
            *(u16x4*)&zbS[(tile0 + g) * 2048 + (P * 16 + lo) * 16 + hi * 4] = pk;
            s1 += __shfl_xor(s1, 16); s2 += __shfl_xor(s2, 16);
            s1 += __shfl_xor(s1, 32); s2 += __shfl_xor(s2, 32);
            if (hi == 0) {
                atomicAdd(&bn_s[P * 16 + lo], s1);
                atomicAdd(&bn_s[128 + P * 16 + lo], s2);
            }
        }
    }
    __syncthreads();
    atomicAdd(&bn1_slots[(blockIdx.x & 63) * 256 + t], bn_s[t]);
}

// Streaming apply v2: one thread owns one (atom, col). Reads its 12 z'f and
// 12 z'c as 6x u16x4 (no shuffles), BN1-apply + sig*softplus, m-sum -> sout,
// BN2 stats via 2 LDS atomics at the end.
__global__ __launch_bounds__(256, 8)
void k_zapply2(const __hip_bfloat16* __restrict__ zb,
               const float* __restrict__ sc1, const float* __restrict__ sh1,
               float* __restrict__ sout, float* __restrict__ bn2_slots) {
    __shared__ float bn_s[128];
    __shared__ float sc_s[128], sh_s[128];
    const int t = threadIdx.x;
    if (t < 128) { bn_s[t] = 0.f; sc_s[t] = sc1[t]; sh_s[t] = sh1[t]; }
    __syncthreads();

    const int a = blockIdx.x * 4 + (t >> 6);
    const int c = t & 63;
    const float s_f = sc_s[c], h_f = sh_s[c];
    const float s_c = sc_s[64 + c], h_c = sh_s[64 + c];
    const short* zs = (const short*)zb;
    const long e0 = (long)a * 12;

    float pv = 0.f;
#pragma unroll
    for (int k = 0; k < 3; ++k) {
        const long e = e0 + k * 4;
        const long tile = e >> 4;
        const int r = (int)(e & 15);
        const short* base = zs + tile * 2048 + r;
        u16x4 zf = *(const u16x4*)&base[c * 16];
        u16x4 zc = *(const u16x4*)&base[(64 + c) * 16];
#pragma unroll
        for (int qq = 0; qq < 4; ++qq) {
            float zfh = bf2f(zf[qq]) * s_f + h_f;
            float zch = bf2f(zc[qq]) * s_c + h_c;
            float filt = 1.f / (1.f + __expf(-zfh));
            pv += filt * softplus_f(zch);
        }
    }
    sout[(long)a * FDIM + c] = pv;
    atomicAdd(&bn_s[c], pv);
    atomicAdd(&bn_s[64 + c], pv * pv);
    __syncthreads();
    if (t < 128)
        atomicAdd(&bn2_slots[(blockIdx.x & 63) * 128 + t], bn_s[t]);
}

// Fallback edge kernel (r11 structure, per-atom tiles with pad masking).
template <int APPLY>
__global__ __launch_bounds__(256, 4)
void k_edge(const __hip_bfloat16* __restrict__ xb,
            const __hip_bfloat16* __restrict__ nbrb,
            const __hip_bfloat16* __restrict__ ballf,
            const __hip_bfloat16* __restrict__ aS,
            const int* __restrict__ idxp,
            const float* __restrict__ sc1, const float* __restrict__ sh1,
            float* __restrict__ bn1_slots,
            float* __restrict__ sout, float* __restrict__ bn2_slots) {
    __shared__ float bn_s[256];
    __shared__ float sc_s[128], sh_s[128];

    const int t = threadIdx.x;
    const int w = t >> 6, l = t & 63;
    const int lo = l & 15, hi = l >> 4;
    const bool real = lo < MNBR;
    const int elo = real ? lo : 0;
    const int atom0 = blockIdx.x * 16 + w * 4;
    const short* xbS = (const short*)xb;
    const short* nbS = (const short*)nbrb;
    const short* aSS = (const short*)aS;
    const short* bb  = (const short*)ballf;

    bn_s[t] = 0.f;
    if (APPLY && t < 128) { sc_s[t] = sc1[t]; sh_s[t] = sh1[t]; }
    __syncthreads();

    const bf16x8 zz = {0, 0, 0, 0, 0, 0, 0, 0};
    const int off1 = (hi < 2) ? (32 + hi * 8) : 0;

#pragma unroll 1
    for (int pr = 0; pr < 2; ++pr) {
        const int a0 = atom0 + pr * 2;
        const int a1 = a0 + 1;
        const int j0 = idxp[(long)a0 * MNBR + elo];
        const int j1 = idxp[(long)a1 * MNBR + elo];
        const short* xj0 = xbS + (long)j0 * FDIM + hi * 8;
        const short* xj1 = xbS + (long)j1 * FDIM + hi * 8;
        const short* nb0 = nbS + ((long)a0 * MNBR + elo) * KP48;
        const short* nb1 = nbS + ((long)a1 * MNBR + elo) * KP48;
        bf16x8 A00 = *(const bf16x8*)(xj0);
        bf16x8 A01 = *(const bf16x8*)(xj0 + 32);
        bf16x8 A02 = *(const bf16x8*)(nb0 + hi * 8);
        bf16x8 n03 = *(const bf16x8*)(nb0 + off1);
        bf16x8 A03 = (hi < 2) ? n03 : zz;
        bf16x8 A10 = *(const bf16x8*)(xj1);
        bf16x8 A11 = *(const bf16x8*)(xj1 + 32);
        bf16x8 A12 = *(const bf16x8*)(nb1 + hi * 8);
        bf16x8 n13 = *(const bf16x8*)(nb1 + off1);
        bf16x8 A13 = (hi < 2) ? n13 : zz;

        if (APPLY == 0) {
#pragma unroll 2
            for (int P = 0; P < 8; ++P) {
                const short* bp = bb + P * 2048 + l * 8;
                bf16x8 B0 = *(const bf16x8*)(bp);
                bf16x8 B1 = *(const bf16x8*)(bp + 512);
                bf16x8 B2 = *(const bf16x8*)(bp + 1024);
                bf16x8 B3 = *(const bf16x8*)(bp + 1536);
                float a0v = bf2f((unsigned short)aSS[(long)a0 * C2 + P * 16 + lo]);
                float a1v = bf2f((unsigned short)aSS[(long)a1 * C2 + P * 16 + lo]);
                f32x4 z0 = {0.f, 0.f, 0.f, 0.f}, z1 = {0.f, 0.f, 0.f, 0.f};
                z0 = __builtin_amdgcn_mfma_f32_16x16x32_bf16(A00, B0, z0, 0, 0, 0);
                z1 = __builtin_amdgcn_mfma_f32_16x16x32_bf16(A10, B0, z1, 0, 0, 0);
                z0 = __builtin_amdgcn_mfma_f32_16x16x32_bf16(A01, B1, z0, 0, 0, 0);
                z1 = __builtin_amdgcn_mfma_f32_16x16x32_bf16(A11, B1, z1, 0, 0, 0);
                z0 = __builtin_amdgcn_mfma_f32_16x16x32_bf16(A02, B2, z0, 0, 0, 0);
                z1 = __builtin_amdgcn_mfma_f32_16x16x32_bf16(A12, B2, z1, 0, 0, 0);
                z0 = __builtin_amdgcn_mfma_f32_16x16x32_bf16(A03, B3, z0, 0, 0, 0);
                z1 = __builtin_amdgcn_mfma_f32_16x16x32_bf16(A13, B3, z1, 0, 0, 0);
#pragma unroll
                for (int g = 0; g < 2; ++g) {
                    f32x4 z = g ? z1 : z0;
                    float av = g ? a1v : a0v;
                    float sz = z[0] + z[1] + z[2] + z[3];
                    float szz = z[0] * z[0] + z[1] * z[1] + z[2] * z[2] + z[3] * z[3];
                    float s1 = sz + 4.f * av;
                    float s2 = szz + 2.f * av * sz + 4.f * av * av;
                    if (hi == 3) { s1 = 0.f; s2 = 0.f; }
                    s1 += __shfl_xor(s1, 16); s2 += __shfl_xor(s2, 16);
                    s1 += __shfl_xor(s1, 32); s2 += __shfl_xor(s2, 32);
                    if (hi == 0) {
                        atomicAdd(&bn_s[P * 16 + lo], s1);
                        atomicAdd(&bn_s[128 + P * 16 + lo], s2);
                    }
                }
            }
        } else {
#pragma unroll 1
            for (int P = 0; P < 4; ++P) {
                const short* bpf = bb + P * 2048 + l * 8;
                const short* bpc = bb + (P + 4) * 2048 + l * 8;
                bf16x8 Bf0 = *(const bf16x8*)(bpf);
                bf16x8 Bf1 = *(const bf16x8*)(bpf + 512);
                bf16x8 Bf2 = *(const bf16x8*)(bpf + 1024);
                bf16x8 Bf3 = *(const bf16x8*)(bpf + 1536);
                bf16x8 Bc0 = *(const bf16x8*)(bpc);
                bf16x8 Bc1 = *(const bf16x8*)(bpc + 512);
                bf16x8 Bc2 = *(const bf16x8*)(bpc + 1024);
                bf16x8 Bc3 = *(const bf16x8*)(bpc + 1536);
                const int c = P * 16 + lo;
                const float s_f = sc_s[c], h_f = sh_s[c];
                const float s_c = sc_s[64 + c], h_c = sh_s[64 + c];
                float hv0f = bf2f((unsigned short)aSS[(long)a0 * C2 + c]) * s_f + h_f;
                float hv0c = bf2f((unsigned short)aSS[(long)a0 * C2 + 64 + c]) * s_c + h_c;
                float hv1f = bf2f((unsigned short)aSS[(long)a1 * C2 + c]) * s_f + h_f;
                float hv1c = bf2f((unsigned short)aSS[(long)a1 * C2 + 64 + c]) * s_c + h_c;
                f32x4 zf0 = {0.f, 0.f, 0.f, 0.f}, zc0 = {0.f, 0.f, 0.f, 0.f};
                f32x4 zf1 = {0.f, 0.f, 0.f, 0.f}, zc1 = {0.f, 0.f, 0.f, 0.f};
                zf0 = __builtin_amdgcn_mfma_f32_16x16x32_bf16(A00, Bf0, zf0, 0, 0, 0);
                zc0 = __builtin_amdgcn_mfma_f32_16x16x32_bf16(A00, Bc0, zc0, 0, 0, 0);
                zf1 = __builtin_amdgcn_mfma_f32_16x16x32_bf16(A10, Bf0, zf1, 0, 0, 0);
                zc1 = __builtin_amdgcn_mfma_f32_16x16x32_bf16(A10, Bc0, zc1, 0, 0, 0);
                zf0 = __builtin_amdgcn_mfma_f32_16x16x32_bf16(A01, Bf1, zf0, 0, 0, 0);
                zc0 = __builtin_amdgcn_mfma_f32_16x16x32_bf16(A01, Bc1, zc0, 0, 0, 0);
                zf1 = __builtin_amdgcn_mfma_f32_16x16x32_bf16(A11, Bf1, zf1, 0, 0, 0);
                zc1 = __builtin_amdgcn_mfma_f32_16x16x32_bf16(A11, Bc1, zc1, 0, 0, 0);
                zf0 = __builtin_amdgcn_mfma_f32_16x16x32_bf16(A02, Bf2, zf0, 0, 0, 0);
                zc0 = __builtin_amdgcn_mfma_f32_16x16x32_bf16(A02, Bc2, zc0, 0, 0, 0);
                zf1 = __builtin_amdgcn_mfma_f32_16x16x32_bf16(A12, Bf2, zf1, 0, 0, 0);
                zc1 = __builtin_amdgcn_mfma_f32_16x16x32_bf16(A12, Bc2, zc1, 0, 0, 0);
                zf0 = __builtin_amdgcn_mfma_f32_16x16x32_bf16(A03, Bf3, zf0, 0, 0, 0);
                zc0 = __builtin_amdgcn_mfma_f32_16x16x32_bf16(A03, Bc3, zc0, 0, 0, 0);
                zf1 = __builtin_amdgcn_mfma_f32_16x16x32_bf16(A13, Bf3, zf1, 0, 0, 0);
                zc1 = __builtin_amdgcn_mfma_f32_16x16x32_bf16(A13, Bc3, zc1, 0, 0, 0);
#pragma unroll
                for (int g = 0; g < 2; ++g) {
                    f32x4 zf = g ? zf1 : zf0;
                    f32x4 zc = g ? zc1 : zc0;
                    float hvf = g ? hv1f : hv0f;
                    float hvc = g ? hv1c : hv0c;
                    float pvsum = 0.f;
#pragma unroll
                    for (int qq = 0; qq < 4; ++qq) {
                        float zfh = zf[qq] * s_f + hvf;
                        float zch = zc[qq] * s_c + hvc;
                        float filt = 1.f / (1.f + __expf(-zfh));
                        pvsum += filt * softplus_f(zch);
                    }
                    if (hi == 3) pvsum = 0.f;
                    pvsum += __shfl_xor(pvsum, 16);
                    pvsum += __shfl_xor(pvsum, 32);
                    if (hi == 0) {
                        sout[(long)(g ? a1 : a0) * FDIM + c] = pvsum;
                        atomicAdd(&bn_s[c], pvsum);
                        atomicAdd(&bn_s[64 + c], pvsum * pvsum);
                    }
                }
            }
        }
    }

    __syncthreads();
    if (APPLY == 0) {
        atomicAdd(&bn1_slots[(blockIdx.x & 63) * 256 + t], bn_s[t]);
    } else {
        if (t < 128)
            atomicAdd(&bn2_slots[(blockIdx.x & 63) * 128 + t], bn_s[t]);
    }
}

// reduce 64 slots -> scale/shift; zero slots for next layer.
__global__ void k_bnfin(float* __restrict__ slots, const float* __restrict__ gamma,
                        const float* __restrict__ beta,
                        float* __restrict__ scale, float* __restrict__ shift,
                        float inv_cnt, int nc) {
    int c = threadIdx.x;
    if (c >= nc) return;
    float s1 = 0.f, s2 = 0.f;
    for (int s = 0; s < 64; ++s) {
        s1 += slots[s * 2 * nc + c];
        s2 += slots[s * 2 * nc + nc + c];
    }
    for (int s = 0; s < 64; ++s) {
        slots[s * 2 * nc + c] = 0.f;
        slots[s * 2 * nc + nc + c] = 0.f;
    }
    float mu = s1 * inv_cnt;
    float var = fmaxf(s2 * inv_cnt - mu * mu, 0.f);
    float sc = gamma[c] * rsqrtf(var + EPSBN);
    scale[c] = sc;
    shift[c] = beta[c] - mu * sc;
}

// x = softplus(x + bn2(s)); also refresh xb
__global__ void k_x(float* __restrict__ x, __hip_bfloat16* __restrict__ xb,
                    const float* __restrict__ s,
                    const float* __restrict__ scale2, const float* __restrict__ shift2) {
    long i = (long)blockIdx.x * 256 + threadIdx.x;
    if (i >= (long)NATOM * FDIM) return;
    int c = (int)(i & 63);
    float v = softplus_f(x[i] + s[i] * scale2[c] + shift2[c]);
    x[i] = v;
    xb[i] = __float2bfloat16(v);
}

__global__ void k_pool(const float* __restrict__ x, const int* __restrict__ seg,
                       float* __restrict__ cry, float* __restrict__ cnt) {
    long i = (long)blockIdx.x * 256 + threadIdx.x;
    if (i >= (long)NATOM * FDIM) return;
    int n = (int)(i >> 6), c = (int)(i & 63);
    int cr = seg[n];
    atomicAdd(&cry[(long)cr * FDIM + c], x[i]);
    if (c == 0) atomicAdd(&cnt[cr], 1.f);
}

__global__ __launch_bounds__(256)
void k_head(const float* __restrict__ cry, const float* __restrict__ cnt,
            const float* __restrict__ fw, const float* __restrict__ fb,
            const float* __restrict__ hw, const float* __restrict__ hb,
            const float* __restrict__ ow, const float* __restrict__ ob,
            float* __restrict__ out) {
    __shared__ float cs[64], h1[128], red[256];
    int t = threadIdx.x, cr = blockIdx.x;
    if (t < 64) cs[t] = cry[(long)cr * 64 + t] / fmaxf(cnt[cr], 1.f);
    __syncthreads();
    if (t < 128) {
        float a = fb[t];
        for (int k = 0; k < 64; ++k) a += cs[k] * fw[k * 128 + t];
        h1[t] = fmaxf(a, 0.f);
    }
    __syncthreads();
    float a = hb[t];
    for (int k = 0; k < 128; ++k) a += h1[k] * hw[k * 256 + t];
    red[t] = a * ow[t];
    __syncthreads();
    for (int off = 128; off > 0; off >>= 1) {
        if (t < off) red[t] += red[t + off];
        __syncthreads();
    }
    if (t == 0) out[cr] = red[0] + ob[0];
}

extern "C" void kernel_launch(void* const* d_in, const int* in_sizes, int n_in,
                              void* d_out, int out_size, void* d_ws, size_t ws_size,
                              hipStream_t stream) {
    const float* atom_fea = (const float*)d_in[0];
    const float* nbr_fea  = (const float*)d_in[1];
    const int*   nbr_idx  = (const int*)d_in[2];
    const int*   seg      = (const int*)d_in[3];
    const float* emb_w    = (const float*)d_in[4];
    const float* emb_b    = (const float*)d_in[5];
    const float* conv_w   = (const float*)d_in[6];
    const float* bn1_g    = (const float*)d_in[8];
    const float* bn1_b    = (const float*)d_in[9];
    const float* bn2_g    = (const float*)d_in[10];
    const float* bn2_b    = (const float*)d_in[11];
    const float* fc_w     = (const float*)d_in[12];
    const float* fc_b     = (const float*)d_in[13];
    const float* head_w   = (const float*)d_in[14];
    const float* head_b   = (const float*)d_in[15];
    const float* out_w    = (const float*)d_in[16];
    const float* out_b    = (const float*)d_in[17];
    float* out = (float*)d_out;

    float* ws = (float*)d_ws;
    float* x = ws + X_OFF;
    __hip_bfloat16* xb     = (__hip_bfloat16*)(ws + XB_OFF);
    float* s = ws + S_OFF;
    __hip_bfloat16* nbrb   = (__hip_bfloat16*)(ws + NBRB_OFF);
    __hip_bfloat16* aS     = (__hip_bfloat16*)(ws + AS_OFF);
    __hip_bfloat16* ballf  = (__hip_bfloat16*)(ws + BALL_OFF);
    __hip_bfloat16* ballfS = (__hip_bfloat16*)(ws + BALLS_OFF);
    float* bn1s = ws + BN1S_OFF;
    float* bn2s = ws + BN2S_OFF;
    float* sc1 = ws + SC1_OFF;
    float* sh1 = ws + SH1_OFF;
    float* sc2 = ws + SC2_OFF;
    float* sh2 = ws + SH2_OFF;
    float* cry = ws + CRY_OFF;
    float* cnt = ws + CNT_OFF;
    __hip_bfloat16* zb = (__hip_bfloat16*)(ws + ZB_OFF);
    const bool fused = (ws_size >= (size_t)WS_NEED_FUSED);

    k_zero<<<(int)((ZERO_CNT + 255) / 256), 256, 0, stream>>>(ws + ZERO_OFF, ZERO_CNT);
    k_nbrcvt<<<(int)(((long)NEDGE * 6 + 255) / 256), 256, 0, stream>>>(nbr_fea, nbrb);
    k_embed<<<NATOM / 16, 256, 0, stream>>>(atom_fea, emb_w, emb_b, x, xb);

    for (int i = 0; i < 3; ++i) {
        const float* cw = conv_w + (long)i * 169 * C2;
        k_bcvt<<<96, 256, 0, stream>>>(cw, ballf, ballfS);
        k_lin<<<1563, 256, 0, stream>>>(xb, ballfS, aS);
        if (fused) {
            k_edge_dense<<<9375, 256, 0, stream>>>(xb, nbrb, ballf, aS, nbr_idx, bn1s, zb);
            k_bnfin<<<1, 128, 0, stream>>>(bn1s, bn1_g + i * C2, bn1_b + i * C2,
                                           sc1, sh1, 1.f / 1200000.f, 128);
            k_zapply2<<<NATOM / 4, 256, 0, stream>>>(zb, sc1, sh1, s, bn2s);
        } else {
            k_edge<0><<<NATOM / 16, 256, 0, stream>>>(xb, nbrb, ballf, aS, nbr_idx,
                                                      nullptr, nullptr, bn1s, nullptr, nullptr);
            k_bnfin<<<1, 128, 0, stream>>>(bn1s, bn1_g + i * C2, bn1_b + i * C2,
                                           sc1, sh1, 1.f / 1200000.f, 128);
            k_edge<1><<<NATOM / 16, 256, 0, stream>>>(xb, nbrb, ballf, aS, nbr_idx,
                                                      sc1, sh1, nullptr, s, bn2s);
        }
        k_bnfin<<<1, 64, 0, stream>>>(bn2s, bn2_g + i * 64, bn2_b + i * 64,
                                      sc2, sh2, 1e-5f, 64);
        k_x<<<(NATOM * FDIM) / 256, 256, 0, stream>>>(x, xb, s, sc2, sh2);
    }

    k_pool<<<(NATOM * FDIM) / 256, 256, 0, stream>>>(x, seg, cry, cnt);
    k_head<<<2000, 256, 0, stream>>>(cry, cnt, fc_w, fc_b, head_w, head_b, out_w, out_b, out);
}

// Round 16
// 1215.412 us; speedup vs baseline: 1.3979x; 1.0090x over previous
//
#include <hip/hip_runtime.h>
#include <hip/hip_bf16.h>

#define NATOM 100000
#define MNBR  12
#define FDIM  64
#define BDIM  41
#define C2    128
#define EPSBN 1e-5f
#define NEDGE (NATOM * MNBR)   // 1,200,000
#define KP48  48               // nbr packed width (41 real + 7 zero), 96B rows
#define NFRAG  16384           // edge B frag-linear: 8T * 4s * 64l * 8e (rows 64..168)
#define NFRAGS 8192            // self B frag-linear: 8T * 2s * 64l * 8e (rows 0..63)

typedef __attribute__((ext_vector_type(8))) short bf16x8;
typedef __attribute__((ext_vector_type(4))) unsigned short u16x4;
typedef __attribute__((ext_vector_type(4))) float f32x4;

// ---- ws layout (float units) ----
#define X_OFF    0L            // x: N*64 f32 (master)
#define XB_OFF   6400000L      // xb: N*64 bf16
#define S_OFF    9600000L      // nbr_sumed: N*64 f32
#define NBRB_OFF 16000000L     // nbr bf16 packed 48-wide: 1.2M*48 bf16 (28.8M floats)
#define AS_OFF   54400000L     // a = x@W_self: N*128 bf16 (6.4M floats)
#define BALL_OFF 60800000L     // edge B frag bf16: 16384 elems (8192 floats)
#define BALLS_OFF 60808192L    // self B frag bf16: 8192 elems (4096 floats)
#define BN1S_OFF 60812288L     // 3 layers * 64 slots * 256 = 49152
#define BN2S_OFF 60861440L     // 3 layers * 64 slots * 128 = 24576
#define CRY_OFF  60886016L     // 2000*64
#define CNT_OFF  61014016L     // 2000
#define SC1_OFF  61016016L     // 128 (fallback only)
#define SH1_OFF  61016144L     // 128 (fallback only)
#define ZB_OFF   61016272L     // z bf16: 75000 tiles * 2048 shorts (76.8M floats)
#define WS_NEED_FUSED ((ZB_OFF + 76800000L) * 4L)
#define ZERO_OFF BN1S_OFF
#define ZERO_CNT 203728L       // slots(49152+24576) + cry(128000) + cnt(2000)

__device__ __forceinline__ float bf2f(unsigned short u) {
    return __uint_as_float(((unsigned)u) << 16);
}
__device__ __forceinline__ unsigned short f2bf(float f) {
    __hip_bfloat16 h = __float2bfloat16(f);
    return *(unsigned short*)&h;
}
__device__ __forceinline__ float softplus_f(float v) {
    return fmaxf(v, 0.f) + __logf(1.f + __expf(-fabsf(v)));
}

__global__ void k_zero(float* __restrict__ p, long cnt) {
    long i = (long)blockIdx.x * 256 + threadIdx.x;
    if (i < cnt) p[i] = 0.f;
}

// nbr_fea f32 [1.2M][41] -> bf16 [1.2M][48] zero-padded; short8-vectorized writes
__global__ void k_nbrcvt(const float* __restrict__ nbr, __hip_bfloat16* __restrict__ outb) {
    long i = (long)blockIdx.x * 256 + threadIdx.x;
    if (i >= (long)NEDGE * 6) return;
    long e = i / 6;
    int c = (int)(i - e * 6);
    const float* src = nbr + e * BDIM + c * 8;
    bf16x8 v;
#pragma unroll
    for (int j = 0; j < 8; ++j) {
        int k = c * 8 + j;
        float f = (k < BDIM) ? src[j] : 0.f;
        v[j] = (short)f2bf(f);
    }
    *(bf16x8*)((short*)outb + e * KP48 + c * 8) = v;
}

// Fragment-linear B for both GEMMs.
__global__ void k_bcvt(const float* __restrict__ cw, __hip_bfloat16* __restrict__ ballf,
                       __hip_bfloat16* __restrict__ ballfS) {
    int i = blockIdx.x * 256 + threadIdx.x;
    if (i < NFRAG) {
        int T = i / 2048, r = i - T * 2048;
        int lidx = (r >> 3) & 63, e = i & 7;
        int s4 = r >> 9;
        int lo = lidx & 15, hi = lidx >> 4;
        int krow = 64 + s4 * 32 + hi * 8 + e;
        float v = (krow < 169) ? cw[krow * C2 + T * 16 + lo] : 0.f;
        ballf[i] = __float2bfloat16(v);
    } else if (i < NFRAG + NFRAGS) {
        int i2 = i - NFRAG;
        int T = i2 / 1024, r = i2 - T * 1024;
        int lidx = (r >> 3) & 63, e = i2 & 7;
        int s = r >> 9;
        int lo = lidx & 15, hi = lidx >> 4;
        int krow = s * 32 + hi * 8 + e;   // 0..63
        ballfS[i2] = __float2bfloat16(cw[krow * C2 + T * 16 + lo]);
    }
}

__global__ __launch_bounds__(256)
void k_embed(const float* __restrict__ af, const float* __restrict__ ew,
             const float* __restrict__ eb, float* __restrict__ x,
             __hip_bfloat16* __restrict__ xb) {
    int t = threadIdx.x;
    int c = t & 63, ag = t >> 6;
    long n0 = (long)blockIdx.x * 16 + ag * 4;
    float acc[4] = {0.f, 0.f, 0.f, 0.f};
    for (int k4 = 0; k4 < 23; ++k4) {
        float w0 = ew[(4 * k4 + 0) * FDIM + c];
        float w1 = ew[(4 * k4 + 1) * FDIM + c];
        float w2 = ew[(4 * k4 + 2) * FDIM + c];
        float w3 = ew[(4 * k4 + 3) * FDIM + c];
#pragma unroll
        for (int a = 0; a < 4; ++a) {
            const float4* ar = (const float4*)(af + (n0 + a) * 92);
            float4 v = ar[k4];
            acc[a] += v.x * w0 + v.y * w1 + v.z * w2 + v.w * w3;
        }
    }
    float b = eb[c];
#pragma unroll
    for (int a = 0; a < 4; ++a) {
        float v = acc[a] + b;
        x[(n0 + a) * FDIM + c] = v;
        xb[(n0 + a) * FDIM + c] = __float2bfloat16(v);
    }
}

// aS = xb @ W_self via MFMA: one 16-atom tile per wave (A rows = atoms).
__global__ __launch_bounds__(256, 8)
void k_lin(const __hip_bfloat16* __restrict__ xb, const __hip_bfloat16* __restrict__ ballfS,
           __hip_bfloat16* __restrict__ aS) {
    int t = threadIdx.x, w = t >> 6, l = t & 63;
    int lo = l & 15, hi = l >> 4;
    long atom0 = ((long)blockIdx.x * 4 + w) * 16;
    if (atom0 >= NATOM) return;
    const short* xs = (const short*)xb + (atom0 + lo) * FDIM + hi * 8;
    bf16x8 A0 = *(const bf16x8*)(xs);
    bf16x8 A1 = *(const bf16x8*)(xs + 32);
    const short* bS = (const short*)ballfS;
#pragma unroll
    for (int T = 0; T < 8; ++T) {
        bf16x8 B0 = *(const bf16x8*)(bS + T * 1024 + l * 8);
        bf16x8 B1 = *(const bf16x8*)(bS + T * 1024 + 512 + l * 8);
        f32x4 z = {0.f, 0.f, 0.f, 0.f};
        z = __builtin_amdgcn_mfma_f32_16x16x32_bf16(A0, B0, z, 0, 0, 0);
        z = __builtin_amdgcn_mfma_f32_16x16x32_bf16(A1, B1, z, 0, 0, 0);
#pragma unroll
        for (int qq = 0; qq < 4; ++qq)
            aS[(atom0 + hi * 4 + qq) * C2 + T * 16 + lo] = __float2bfloat16(z[qq]);
    }
}

// Dense stats+store pass: 16-edge tiles. Per wave 2 tiles sharing every B
// fragment. Self-term indices hoisted: per (g,thread) the 4 rows span <=2
// atoms -> n0/n3/bnd computed once (4 divs/thread, not 64); 2 aS loads per
// (P,g) with per-qq cndmask select. z' stored bf16 at zb[tile*2048+col*16+row].
__global__ __launch_bounds__(256, 4)
void k_edge_dense(const __hip_bfloat16* __restrict__ xb,
                  const __hip_bfloat16* __restrict__ nbrb,
                  const __hip_bfloat16* __restrict__ ballf,
                  const __hip_bfloat16* __restrict__ aS,
                  const int* __restrict__ idxp,
                  float* __restrict__ bn1_slots,
                  __hip_bfloat16* __restrict__ zb) {
    __shared__ float bn_s[256];
    const int t = threadIdx.x;
    const int w = t >> 6, l = t & 63;
    const int lo = l & 15, hi = l >> 4;
    const short* xbS = (const short*)xb;
    const short* nbS = (const short*)nbrb;
    const short* aSS = (const short*)aS;
    const short* bb  = (const short*)ballf;
    short* zbS = (short*)zb;

    bn_s[t] = 0.f;
    __syncthreads();

    const long tile0 = (long)blockIdx.x * 8 + w * 2;   // tiles tile0, tile0+1
    const bf16x8 zz = {0, 0, 0, 0, 0, 0, 0, 0};
    const int off1 = (hi < 2) ? (32 + hi * 8) : 0;

    bf16x8 A[2][4];
    long aLo[2], aHi[2];
    int bnd[2];
#pragma unroll
    for (int g = 0; g < 2; ++g) {
        const long e0 = (tile0 + g) * 16;
        const int j = idxp[e0 + lo];
        const short* xj = xbS + (long)j * FDIM + hi * 8;
        const short* nb = nbS + (e0 + lo) * KP48;
        A[g][0] = *(const bf16x8*)(xj);
        A[g][1] = *(const bf16x8*)(xj + 32);
        A[g][2] = *(const bf16x8*)(nb + hi * 8);
        bf16x8 n1 = *(const bf16x8*)(nb + off1);
        A[g][3] = (hi < 2) ? n1 : zz;
        // self-term atom indices for this thread's 4 rows (span <=2 atoms)
        const int rbase = (int)e0 + hi * 4;
        const int n0 = rbase / 12;
        const int n3 = (rbase + 3) / 12;
        aLo[g] = (long)n0 * C2;
        aHi[g] = (long)n3 * C2;
        bnd[g] = (n3 > n0) ? (n3 * 12 - rbase) : 4;   // qq >= bnd -> n3
    }

#pragma unroll 2
    for (int P = 0; P < 8; ++P) {
        const short* bp = bb + P * 2048 + l * 8;
        bf16x8 B0 = *(const bf16x8*)(bp);
        bf16x8 B1 = *(const bf16x8*)(bp + 512);
        bf16x8 B2 = *(const bf16x8*)(bp + 1024);
        bf16x8 B3 = *(const bf16x8*)(bp + 1536);
        f32x4 z0 = {0.f, 0.f, 0.f, 0.f}, z1 = {0.f, 0.f, 0.f, 0.f};
        z0 = __builtin_amdgcn_mfma_f32_16x16x32_bf16(A[0][0], B0, z0, 0, 0, 0);
        z1 = __builtin_amdgcn_mfma_f32_16x16x32_bf16(A[1][0], B0, z1, 0, 0, 0);
        z0 = __builtin_amdgcn_mfma_f32_16x16x32_bf16(A[0][1], B1, z0, 0, 0, 0);
        z1 = __builtin_amdgcn_mfma_f32_16x16x32_bf16(A[1][1], B1, z1, 0, 0, 0);
        z0 = __builtin_amdgcn_mfma_f32_16x16x32_bf16(A[0][2], B2, z0, 0, 0, 0);
        z1 = __builtin_amdgcn_mfma_f32_16x16x32_bf16(A[1][2], B2, z1, 0, 0, 0);
        z0 = __builtin_amdgcn_mfma_f32_16x16x32_bf16(A[0][3], B3, z0, 0, 0, 0);
        z1 = __builtin_amdgcn_mfma_f32_16x16x32_bf16(A[1][3], B3, z1, 0, 0, 0);
        const int col = P * 16 + lo;
#pragma unroll
        for (int g = 0; g < 2; ++g) {
            f32x4 z = g ? z1 : z0;
            const float avlo = bf2f((unsigned short)aSS[aLo[g] + col]);
            const float avhi = bf2f((unsigned short)aSS[aHi[g] + col]);
            float s1 = 0.f, s2 = 0.f;
            u16x4 pk;
#pragma unroll
            for (int qq = 0; qq < 4; ++qq) {
                float av = (qq >= bnd[g]) ? avhi : avlo;
                float zp = z[qq] + av;
                pk[qq] = f2bf(zp);
                s1 += zp;
                s2 += zp * zp;
            }
            *(u16x4*)&zbS[(tile0 + g) * 2048 + col * 16 + hi * 4] = pk;
            s1 += __shfl_xor(s1, 16); s2 += __shfl_xor(s2, 16);
            s1 += __shfl_xor(s1, 32); s2 += __shfl_xor(s2, 32);
            if (hi == 0) {
                atomicAdd(&bn_s[col], s1);
                atomicAdd(&bn_s[128 + col], s2);
            }
        }
    }
    __syncthreads();
    atomicAdd(&bn1_slots[(blockIdx.x & 63) * 256 + t], bn_s[t]);
}

// Streaming apply (grid-stride): in-block BN1 finalize from slots, then each
// thread owns one (atom, col): 6x u16x4 reads, activation, m-sum -> sout,
// BN2 stats accumulated in registers, flushed once.
__global__ __launch_bounds__(256, 8)
void k_zapply2(const __hip_bfloat16* __restrict__ zb,
               const float* __restrict__ bn1_layer,
               const float* __restrict__ g1, const float* __restrict__ b1,
               float* __restrict__ sout, float* __restrict__ bn2_slots) {
    __shared__ float bn_s[128];
    __shared__ float sc_s[128], sh_s[128];
    const int t = threadIdx.x;
    if (t < 128) {
        float s1 = 0.f, s2 = 0.f;
        for (int sl = 0; sl < 64; ++sl) {
            s1 += bn1_layer[sl * 256 + t];
            s2 += bn1_layer[sl * 256 + 128 + t];
        }
        const float inv = 1.f / 1200000.f;
        float mu = s1 * inv;
        float var = fmaxf(s2 * inv - mu * mu, 0.f);
        float sc = g1[t] * rsqrtf(var + EPSBN);
        sc_s[t] = sc;
        sh_s[t] = b1[t] - mu * sc;
        bn_s[t] = 0.f;
    }
    __syncthreads();

    const int c = t & 63;
    const float s_f = sc_s[c], h_f = sh_s[c];
    const float s_c = sc_s[64 + c], h_c = sh_s[64 + c];
    const short* zs = (const short*)zb;
    float racc1 = 0.f, racc2 = 0.f;

    for (int grp = blockIdx.x; grp < NATOM / 4; grp += gridDim.x) {
        const int a = grp * 4 + (t >> 6);
        const long e0 = (long)a * 12;
        float pv = 0.f;
#pragma unroll
        for (int k = 0; k < 3; ++k) {
            const long e = e0 + k * 4;
            const long tile = e >> 4;
            const int r = (int)(e & 15);
            const short* base = zs + tile * 2048 + r;
            u16x4 zf = *(const u16x4*)&base[c * 16];
            u16x4 zc = *(const u16x4*)&base[(64 + c) * 16];
#pragma unroll
            for (int qq = 0; qq < 4; ++qq) {
                float zfh = bf2f(zf[qq]) * s_f + h_f;
                float zch = bf2f(zc[qq]) * s_c + h_c;
                float filt = 1.f / (1.f + __expf(-zfh));
                pv += filt * softplus_f(zch);
            }
        }
        sout[(long)a * FDIM + c] = pv;
        racc1 += pv;
        racc2 += pv * pv;
    }
    atomicAdd(&bn_s[c], racc1);
    atomicAdd(&bn_s[64 + c], racc2);
    __syncthreads();
    if (t < 128)
        atomicAdd(&bn2_slots[(blockIdx.x & 63) * 128 + t], bn_s[t]);
}

// x = softplus(x + bn2(s)) with in-block BN2 finalize from slots; grid-stride.
__global__ __launch_bounds__(256, 8)
void k_x(float* __restrict__ x, __hip_bfloat16* __restrict__ xb,
         const float* __restrict__ s,
         const float* __restrict__ bn2_layer,
         const float* __restrict__ g2, const float* __restrict__ b2) {
    __shared__ float sc_s[64], sh_s[64];
    const int t = threadIdx.x;
    if (t < 64) {
        float s1 = 0.f, s2 = 0.f;
        for (int sl = 0; sl < 64; ++sl) {
            s1 += bn2_layer[sl * 128 + t];
            s2 += bn2_layer[sl * 128 + 64 + t];
        }
        const float inv = 1e-5f;
        float mu = s1 * inv;
        float var = fmaxf(s2 * inv - mu * mu, 0.f);
        float sc = g2[t] * rsqrtf(var + EPSBN);
        sc_s[t] = sc;
        sh_s[t] = b2[t] - mu * sc;
    }
    __syncthreads();
    const long total = (long)NATOM * FDIM;
    const long stride = (long)gridDim.x * 256;
    for (long i = (long)blockIdx.x * 256 + t; i < total; i += stride) {
        int c = (int)(i & 63);
        float v = softplus_f(x[i] + s[i] * sc_s[c] + sh_s[c]);
        x[i] = v;
        xb[i] = __float2bfloat16(v);
    }
}

// ---- fallback path (ws too small for zb): r11 two-pass edge kernel ----
__global__ void k_bnfin(const float* __restrict__ slots, const float* __restrict__ gamma,
                        const float* __restrict__ beta,
                        float* __restrict__ scale, float* __restrict__ shift,
                        float inv_cnt, int nc) {
    int c = threadIdx.x;
    if (c >= nc) return;
    float s1 = 0.f, s2 = 0.f;
    for (int s = 0; s < 64; ++s) {
        s1 += slots[s * 2 * nc + c];
        s2 += slots[s * 2 * nc + nc + c];
    }
    float mu = s1 * inv_cnt;
    float var = fmaxf(s2 * inv_cnt - mu * mu, 0.f);
    float sc = gamma[c] * rsqrtf(var + EPSBN);
    scale[c] = sc;
    shift[c] = beta[c] - mu * sc;
}

template <int APPLY>
__global__ __launch_bounds__(256, 4)
void k_edge(const __hip_bfloat16* __restrict__ xb,
            const __hip_bfloat16* __restrict__ nbrb,
            const __hip_bfloat16* __restrict__ ballf,
            const __hip_bfloat16* __restrict__ aS,
            const int* __restrict__ idxp,
            const float* __restrict__ sc1, const float* __restrict__ sh1,
            float* __restrict__ bn1_slots,
            float* __restrict__ sout, float* __restrict__ bn2_slots) {
    __shared__ float bn_s[256];
    __shared__ float sc_s[128], sh_s[128];

    const int t = threadIdx.x;
    const int w = t >> 6, l = t & 63;
    const int lo = l & 15, hi = l >> 4;
    const bool real = lo < MNBR;
    const int elo = real ? lo : 0;
    const int atom0 = blockIdx.x * 16 + w * 4;
    const short* xbS = (const short*)xb;
    const short* nbS = (const short*)nbrb;
    const short* aSS = (const short*)aS;
    const short* bb  = (const short*)ballf;

    bn_s[t] = 0.f;
    if (APPLY && t < 128) { sc_s[t] = sc1[t]; sh_s[t] = sh1[t]; }
    __syncthreads();

    const bf16x8 zz = {0, 0, 0, 0, 0, 0, 0, 0};
    const int off1 = (hi < 2) ? (32 + hi * 8) : 0;

#pragma unroll 1
    for (int pr = 0; pr < 2; ++pr) {
        const int a0 = atom0 + pr * 2;
        const int a1 = a0 + 1;
        const int j0 = idxp[(long)a0 * MNBR + elo];
        const int j1 = idxp[(long)a1 * MNBR + elo];
        const short* xj0 = xbS + (long)j0 * FDIM + hi * 8;
        const short* xj1 = xbS + (long)j1 * FDIM + hi * 8;
        const short* nb0 = nbS + ((long)a0 * MNBR + elo) * KP48;
        const short* nb1 = nbS + ((long)a1 * MNBR + elo) * KP48;
        bf16x8 A00 = *(const bf16x8*)(xj0);
        bf16x8 A01 = *(const bf16x8*)(xj0 + 32);
        bf16x8 A02 = *(const bf16x8*)(nb0 + hi * 8);
        bf16x8 n03 = *(const bf16x8*)(nb0 + off1);
        bf16x8 A03 = (hi < 2) ? n03 : zz;
        bf16x8 A10 = *(const bf16x8*)(xj1);
        bf16x8 A11 = *(const bf16x8*)(xj1 + 32);
        bf16x8 A12 = *(const bf16x8*)(nb1 + hi * 8);
        bf16x8 n13 = *(const bf16x8*)(nb1 + off1);
        bf16x8 A13 = (hi < 2) ? n13 : zz;

        if (APPLY == 0) {
#pragma unroll 2
            for (int P = 0; P < 8; ++P) {
                const short* bp = bb + P * 2048 + l * 8;
                bf16x8 B0 = *(const bf16x8*)(bp);
                bf16x8 B1 = *(const bf16x8*)(bp + 512);
                bf16x8 B2 = *(const bf16x8*)(bp + 1024);
                bf16x8 B3 = *(const bf16x8*)(bp + 1536);
                float a0v = bf2f((unsigned short)aSS[(long)a0 * C2 + P * 16 + lo]);
                float a1v = bf2f((unsigned short)aSS[(long)a1 * C2 + P * 16 + lo]);
                f32x4 z0 = {0.f, 0.f, 0.f, 0.f}, z1 = {0.f, 0.f, 0.f, 0.f};
                z0 = __builtin_amdgcn_mfma_f32_16x16x32_bf16(A00, B0, z0, 0, 0, 0);
                z1 = __builtin_amdgcn_mfma_f32_16x16x32_bf16(A10, B0, z1, 0, 0, 0);
                z0 = __builtin_amdgcn_mfma_f32_16x16x32_bf16(A01, B1, z0, 0, 0, 0);
                z1 = __builtin_amdgcn_mfma_f32_16x16x32_bf16(A11, B1, z1, 0, 0, 0);
                z0 = __builtin_amdgcn_mfma_f32_16x16x32_bf16(A02, B2, z0, 0, 0, 0);
                z1 = __builtin_amdgcn_mfma_f32_16x16x32_bf16(A12, B2, z1, 0, 0, 0);
                z0 = __builtin_amdgcn_mfma_f32_16x16x32_bf16(A03, B3, z0, 0, 0, 0);
                z1 = __builtin_amdgcn_mfma_f32_16x16x32_bf16(A13, B3, z1, 0, 0, 0);
#pragma unroll
                for (int g = 0; g < 2; ++g) {
                    f32x4 z = g ? z1 : z0;
                    float av = g ? a1v : a0v;
                    float sz = z[0] + z[1] + z[2] + z[3];
                    float szz = z[0] * z[0] + z[1] * z[1] + z[2] * z[2] + z[3] * z[3];
                    float s1 = sz + 4.f * av;
                    float s2 = szz + 2.f * av * sz + 4.f * av * av;
                    if (hi == 3) { s1 = 0.f; s2 = 0.f; }
                    s1 += __shfl_xor(s1, 16); s2 += __shfl_xor(s2, 16);
                    s1 += __shfl_xor(s1, 32); s2 += __shfl_xor(s2, 32);
                    if (hi == 0) {
                        atomicAdd(&bn_s[P * 16 + lo], s1);
                        atomicAdd(&bn_s[128 + P * 16 + lo], s2);
                    }
                }
            }
        } else {
#pragma unroll 1
            for (int P = 0; P < 4; ++P) {
                const short* bpf = bb + P * 2048 + l * 8;
                const short* bpc = bb + (P + 4) * 2048 + l * 8;
                bf16x8 Bf0 = *(const bf16x8*)(bpf);
                bf16x8 Bf1 = *(const bf16x8*)(bpf + 512);
                bf16x8 Bf2 = *(const bf16x8*)(bpf + 1024);
                bf16x8 Bf3 = *(const bf16x8*)(bpf + 1536);
                bf16x8 Bc0 = *(const bf16x8*)(bpc);
                bf16x8 Bc1 = *(const bf16x8*)(bpc + 512);
                bf16x8 Bc2 = *(const bf16x8*)(bpc + 1024);
                bf16x8 Bc3 = *(const bf16x8*)(bpc + 1536);
                const int c = P * 16 + lo;
                const float s_f = sc_s[c], h_f = sh_s[c];
                const float s_c = sc_s[64 + c], h_c = sh_s[64 + c];
                float hv0f = bf2f((unsigned short)aSS[(long)a0 * C2 + c]) * s_f + h_f;
                float hv0c = bf2f((unsigned short)aSS[(long)a0 * C2 + 64 + c]) * s_c + h_c;
                float hv1f = bf2f((unsigned short)aSS[(long)a1 * C2 + c]) * s_f + h_f;
                float hv1c = bf2f((unsigned short)aSS[(long)a1 * C2 + 64 + c]) * s_c + h_c;
                f32x4 zf0 = {0.f, 0.f, 0.f, 0.f}, zc0 = {0.f, 0.f, 0.f, 0.f};
                f32x4 zf1 = {0.f, 0.f, 0.f, 0.f}, zc1 = {0.f, 0.f, 0.f, 0.f};
                zf0 = __builtin_amdgcn_mfma_f32_16x16x32_bf16(A00, Bf0, zf0, 0, 0, 0);
                zc0 = __builtin_amdgcn_mfma_f32_16x16x32_bf16(A00, Bc0, zc0, 0, 0, 0);
                zf1 = __builtin_amdgcn_mfma_f32_16x16x32_bf16(A10, Bf0, zf1, 0, 0, 0);
                zc1 = __builtin_amdgcn_mfma_f32_16x16x32_bf16(A10, Bc0, zc1, 0, 0, 0);
                zf0 = __builtin_amdgcn_mfma_f32_16x16x32_bf16(A01, Bf1, zf0, 0, 0, 0);
                zc0 = __builtin_amdgcn_mfma_f32_16x16x32_bf16(A01, Bc1, zc0, 0, 0, 0);
                zf1 = __builtin_amdgcn_mfma_f32_16x16x32_bf16(A11, Bf1, zf1, 0, 0, 0);
                zc1 = __builtin_amdgcn_mfma_f32_16x16x32_bf16(A11, Bc1, zc1, 0, 0, 0);
                zf0 = __builtin_amdgcn_mfma_f32_16x16x32_bf16(A02, Bf2, zf0, 0, 0, 0);
                zc0 = __builtin_amdgcn_mfma_f32_16x16x32_bf16(A02, Bc2, zc0, 0, 0, 0);
                zf1 = __builtin_amdgcn_mfma_f32_16x16x32_bf16(A12, Bf2, zf1, 0, 0, 0);
                zc1 = __builtin_amdgcn_mfma_f32_16x16x32_bf16(A12, Bc2, zc1, 0, 0, 0);
                zf0 = __builtin_amdgcn_mfma_f32_16x16x32_bf16(A03, Bf3, zf0, 0, 0, 0);
                zc0 = __builtin_amdgcn_mfma_f32_16x16x32_bf16(A03, Bc3, zc0, 0, 0, 0);
                zf1 = __builtin_amdgcn_mfma_f32_16x16x32_bf16(A13, Bf3, zf1, 0, 0, 0);
                zc1 = __builtin_amdgcn_mfma_f32_16x16x32_bf16(A13, Bc3, zc1, 0, 0, 0);
#pragma unroll
                for (int g = 0; g < 2; ++g) {
                    f32x4 zf = g ? zf1 : zf0;
                    f32x4 zc = g ? zc1 : zc0;
                    float hvf = g ? hv1f : hv0f;
                    float hvc = g ? hv1c : hv0c;
                    float pvsum = 0.f;
#pragma unroll
                    for (int qq = 0; qq < 4; ++qq) {
                        float zfh = zf[qq] * s_f + hvf;
                        float zch = zc[qq] * s_c + hvc;
                        float filt = 1.f / (1.f + __expf(-zfh));
                        pvsum += filt * softplus_f(zch);
                    }
                    if (hi == 3) pvsum = 0.f;
                    pvsum += __shfl_xor(pvsum, 16);
                    pvsum += __shfl_xor(pvsum, 32);
                    if (hi == 0) {
                        sout[(long)(g ? a1 : a0) * FDIM + c] = pvsum;
                        atomicAdd(&bn_s[c], pvsum);
                        atomicAdd(&bn_s[64 + c], pvsum * pvsum);
                    }
                }
            }
        }
    }

    __syncthreads();
    if (APPLY == 0) {
        atomicAdd(&bn1_slots[(blockIdx.x & 63) * 256 + t], bn_s[t]);
    } else {
        if (t < 128)
            atomicAdd(&bn2_slots[(blockIdx.x & 63) * 128 + t], bn_s[t]);
    }
}

__global__ void k_pool(const float* __restrict__ x, const int* __restrict__ seg,
                       float* __restrict__ cry, float* __restrict__ cnt) {
    long i = (long)blockIdx.x * 256 + threadIdx.x;
    if (i >= (long)NATOM * FDIM) return;
    int n = (int)(i >> 6), c = (int)(i & 63);
    int cr = seg[n];
    atomicAdd(&cry[(long)cr * FDIM + c], x[i]);
    if (c == 0) atomicAdd(&cnt[cr], 1.f);
}

__global__ __launch_bounds__(256)
void k_head(const float* __restrict__ cry, const float* __restrict__ cnt,
            const float* __restrict__ fw, const float* __restrict__ fb,
            const float* __restrict__ hw, const float* __restrict__ hb,
            const float* __restrict__ ow, const float* __restrict__ ob,
            float* __restrict__ out) {
    __shared__ float cs[64], h1[128], red[256];
    int t = threadIdx.x, cr = blockIdx.x;
    if (t < 64) cs[t] = cry[(long)cr * 64 + t] / fmaxf(cnt[cr], 1.f);
    __syncthreads();
    if (t < 128) {
        float a = fb[t];
        for (int k = 0; k < 64; ++k) a += cs[k] * fw[k * 128 + t];
        h1[t] = fmaxf(a, 0.f);
    }
    __syncthreads();
    float a = hb[t];
    for (int k = 0; k < 128; ++k) a += h1[k] * hw[k * 256 + t];
    red[t] = a * ow[t];
    __syncthreads();
    for (int off = 128; off > 0; off >>= 1) {
        if (t < off) red[t] += red[t + off];
        __syncthreads();
    }
    if (t == 0) out[cr] = red[0] + ob[0];
}

extern "C" void kernel_launch(void* const* d_in, const int* in_sizes, int n_in,
                              void* d_out, int out_size, void* d_ws, size_t ws_size,
                              hipStream_t stream) {
    const float* atom_fea = (const float*)d_in[0];
    const float* nbr_fea  = (const float*)d_in[1];
    const int*   nbr_idx  = (const int*)d_in[2];
    const int*   seg      = (const int*)d_in[3];
    const float* emb_w    = (const float*)d_in[4];
    const float* emb_b    = (const float*)d_in[5];
    const float* conv_w   = (const float*)d_in[6];
    const float* bn1_g    = (const float*)d_in[8];
    const float* bn1_b    = (const float*)d_in[9];
    const float* bn2_g    = (const float*)d_in[10];
    const float* bn2_b    = (const float*)d_in[11];
    const float* fc_w     = (const float*)d_in[12];
    const float* fc_b     = (const float*)d_in[13];
    const float* head_w   = (const float*)d_in[14];
    const float* head_b   = (const float*)d_in[15];
    const float* out_w    = (const float*)d_in[16];
    const float* out_b    = (const float*)d_in[17];
    float* out = (float*)d_out;

    float* ws = (float*)d_ws;
    float* x = ws + X_OFF;
    __hip_bfloat16* xb     = (__hip_bfloat16*)(ws + XB_OFF);
    float* s = ws + S_OFF;
    __hip_bfloat16* nbrb   = (__hip_bfloat16*)(ws + NBRB_OFF);
    __hip_bfloat16* aS     = (__hip_bfloat16*)(ws + AS_OFF);
    __hip_bfloat16* ballf  = (__hip_bfloat16*)(ws + BALL_OFF);
    __hip_bfloat16* ballfS = (__hip_bfloat16*)(ws + BALLS_OFF);
    float* bn1s = ws + BN1S_OFF;
    float* bn2s = ws + BN2S_OFF;
    float* cry = ws + CRY_OFF;
    float* cnt = ws + CNT_OFF;
    float* sc1 = ws + SC1_OFF;
    float* sh1 = ws + SH1_OFF;
    __hip_bfloat16* zb = (__hip_bfloat16*)(ws + ZB_OFF);
    const bool fused = (ws_size >= (size_t)WS_NEED_FUSED);

    k_zero<<<(int)((ZERO_CNT + 255) / 256), 256, 0, stream>>>(ws + ZERO_OFF, ZERO_CNT);
    k_nbrcvt<<<(int)(((long)NEDGE * 6 + 255) / 256), 256, 0, stream>>>(nbr_fea, nbrb);
    k_embed<<<NATOM / 16, 256, 0, stream>>>(atom_fea, emb_w, emb_b, x, xb);

    for (int i = 0; i < 3; ++i) {
        const float* cw = conv_w + (long)i * 169 * C2;
        float* bn1L = bn1s + (long)i * 16384;
        float* bn2L = bn2s + (long)i * 8192;
        k_bcvt<<<96, 256, 0, stream>>>(cw, ballf, ballfS);
        k_lin<<<1563, 256, 0, stream>>>(xb, ballfS, aS);
        if (fused) {
            k_edge_dense<<<9375, 256, 0, stream>>>(xb, nbrb, ballf, aS, nbr_idx, bn1L, zb);
            k_zapply2<<<2048, 256, 0, stream>>>(zb, bn1L, bn1_g + i * C2, bn1_b + i * C2,
                                                s, bn2L);
        } else {
            k_edge<0><<<NATOM / 16, 256, 0, stream>>>(xb, nbrb, ballf, aS, nbr_idx,
                                                      nullptr, nullptr, bn1L, nullptr, nullptr);
            k_bnfin<<<1, 128, 0, stream>>>(bn1L, bn1_g + i * C2, bn1_b + i * C2,
                                           sc1, sh1, 1.f / 1200000.f, 128);
            k_edge<1><<<NATOM / 16, 256, 0, stream>>>(xb, nbrb, ballf, aS, nbr_idx,
                                                      sc1, sh1, nullptr, s, bn2L);
        }
        k_x<<<2048, 256, 0, stream>>>(x, xb, s, bn2L, bn2_g + i * 64, bn2_b + i * 64);
    }

    k_pool<<<(NATOM * FDIM) / 256, 256, 0, stream>>>(x, seg, cry, cnt);
    k_head<<<2000, 256, 0, stream>>>(cry, cnt, fc_w, fc_b, head_w, head_b, out_w, out_b, out);
}

// Round 17
// 1193.794 us; speedup vs baseline: 1.4232x; 1.0181x over previous
//
#include <hip/hip_runtime.h>
#include <hip/hip_bf16.h>

#define NATOM 100000
#define MNBR  12
#define FDIM  64
#define BDIM  41
#define C2    128
#define EPSBN 1e-5f
#define NEDGE (NATOM * MNBR)   // 1,200,000
#define KP48  48               // nbr packed width (41 real + 7 zero), 96B rows
#define NFRAG  16384           // edge B frag-linear: 8T * 4s * 64l * 8e (rows 64..168)
#define NFRAGS 8192            // self B frag-linear: 8T * 2s * 64l * 8e (rows 0..63)

typedef __attribute__((ext_vector_type(8))) short bf16x8;
typedef __attribute__((ext_vector_type(8))) unsigned short u16x8;
typedef __attribute__((ext_vector_type(4))) unsigned short u16x4;
typedef __attribute__((ext_vector_type(4))) float f32x4;

// ---- ws layout (float units) ----
#define X_OFF    0L            // x: N*64 f32 (master)
#define XB_OFF   6400000L      // xb: N*64 bf16
#define S_OFF    9600000L      // nbr_sumed: N*64 f32
#define NBRB_OFF 16000000L     // nbr bf16 packed 48-wide: 1.2M*48 bf16 (28.8M floats)
#define AS_OFF   54400000L     // a = x@W_self: N*128 bf16 (6.4M floats)
#define BALL_OFF 60800000L     // edge B frag bf16: 16384 elems (8192 floats)
#define BALLS_OFF 60808192L    // self B frag bf16: 8192 elems (4096 floats)
#define BN1S_OFF 60812288L     // 3 layers * 64 slots * 256 = 49152
#define BN2S_OFF 60861440L     // 3 layers * 64 slots * 128 = 24576
#define CRY_OFF  60886016L     // 2000*64
#define CNT_OFF  61014016L     // 2000
#define SC1_OFF  61016016L     // 128 (fallback only)
#define SH1_OFF  61016144L     // 128 (fallback only)
#define ZB_OFF   61016272L     // z bf16: 75000 tiles * 2048 shorts (76.8M floats)
#define WS_NEED_FUSED ((ZB_OFF + 76800000L) * 4L)
#define ZERO_OFF BN1S_OFF
#define ZERO_CNT 203728L       // slots(49152+24576) + cry(128000) + cnt(2000)

__device__ __forceinline__ float bf2f(unsigned short u) {
    return __uint_as_float(((unsigned)u) << 16);
}
__device__ __forceinline__ unsigned short f2bf(float f) {
    __hip_bfloat16 h = __float2bfloat16(f);
    return *(unsigned short*)&h;
}
__device__ __forceinline__ float softplus_f(float v) {
    return fmaxf(v, 0.f) + __logf(1.f + __expf(-fabsf(v)));
}

__global__ void k_zero(float* __restrict__ p, long cnt) {
    long i = (long)blockIdx.x * 256 + threadIdx.x;
    if (i < cnt) p[i] = 0.f;
}

// nbr_fea f32 [1.2M][41] -> bf16 [1.2M][48] zero-padded; short8-vectorized writes
__global__ void k_nbrcvt(const float* __restrict__ nbr, __hip_bfloat16* __restrict__ outb) {
    long i = (long)blockIdx.x * 256 + threadIdx.x;
    if (i >= (long)NEDGE * 6) return;
    long e = i / 6;
    int c = (int)(i - e * 6);
    const float* src = nbr + e * BDIM + c * 8;
    bf16x8 v;
#pragma unroll
    for (int j = 0; j < 8; ++j) {
        int k = c * 8 + j;
        float f = (k < BDIM) ? src[j] : 0.f;
        v[j] = (short)f2bf(f);
    }
    *(bf16x8*)((short*)outb + e * KP48 + c * 8) = v;
}

// Fragment-linear B for both GEMMs.
__global__ void k_bcvt(const float* __restrict__ cw, __hip_bfloat16* __restrict__ ballf,
                       __hip_bfloat16* __restrict__ ballfS) {
    int i = blockIdx.x * 256 + threadIdx.x;
    if (i < NFRAG) {
        int T = i / 2048, r = i - T * 2048;
        int lidx = (r >> 3) & 63, e = i & 7;
        int s4 = r >> 9;
        int lo = lidx & 15, hi = lidx >> 4;
        int krow = 64 + s4 * 32 + hi * 8 + e;
        float v = (krow < 169) ? cw[krow * C2 + T * 16 + lo] : 0.f;
        ballf[i] = __float2bfloat16(v);
    } else if (i < NFRAG + NFRAGS) {
        int i2 = i - NFRAG;
        int T = i2 / 1024, r = i2 - T * 1024;
        int lidx = (r >> 3) & 63, e = i2 & 7;
        int s = r >> 9;
        int lo = lidx & 15, hi = lidx >> 4;
        int krow = s * 32 + hi * 8 + e;   // 0..63
        ballfS[i2] = __float2bfloat16(cw[krow * C2 + T * 16 + lo]);
    }
}

__global__ __launch_bounds__(256)
void k_embed(const float* __restrict__ af, const float* __restrict__ ew,
             const float* __restrict__ eb, float* __restrict__ x,
             __hip_bfloat16* __restrict__ xb) {
    int t = threadIdx.x;
    int c = t & 63, ag = t >> 6;
    long n0 = (long)blockIdx.x * 16 + ag * 4;
    float acc[4] = {0.f, 0.f, 0.f, 0.f};
    for (int k4 = 0; k4 < 23; ++k4) {
        float w0 = ew[(4 * k4 + 0) * FDIM + c];
        float w1 = ew[(4 * k4 + 1) * FDIM + c];
        float w2 = ew[(4 * k4 + 2) * FDIM + c];
        float w3 = ew[(4 * k4 + 3) * FDIM + c];
#pragma unroll
        for (int a = 0; a < 4; ++a) {
            const float4* ar = (const float4*)(af + (n0 + a) * 92);
            float4 v = ar[k4];
            acc[a] += v.x * w0 + v.y * w1 + v.z * w2 + v.w * w3;
        }
    }
    float b = eb[c];
#pragma unroll
    for (int a = 0; a < 4; ++a) {
        float v = acc[a] + b;
        x[(n0 + a) * FDIM + c] = v;
        xb[(n0 + a) * FDIM + c] = __float2bfloat16(v);
    }
}

// aS = xb @ W_self via MFMA: one 16-atom tile per wave (A rows = atoms).
__global__ __launch_bounds__(256, 8)
void k_lin(const __hip_bfloat16* __restrict__ xb, const __hip_bfloat16* __restrict__ ballfS,
           __hip_bfloat16* __restrict__ aS) {
    int t = threadIdx.x, w = t >> 6, l = t & 63;
    int lo = l & 15, hi = l >> 4;
    long atom0 = ((long)blockIdx.x * 4 + w) * 16;
    if (atom0 >= NATOM) return;
    const short* xs = (const short*)xb + (atom0 + lo) * FDIM + hi * 8;
    bf16x8 A0 = *(const bf16x8*)(xs);
    bf16x8 A1 = *(const bf16x8*)(xs + 32);
    const short* bS = (const short*)ballfS;
#pragma unroll
    for (int T = 0; T < 8; ++T) {
        bf16x8 B0 = *(const bf16x8*)(bS + T * 1024 + l * 8);
        bf16x8 B1 = *(const bf16x8*)(bS + T * 1024 + 512 + l * 8);
        f32x4 z = {0.f, 0.f, 0.f, 0.f};
        z = __builtin_amdgcn_mfma_f32_16x16x32_bf16(A0, B0, z, 0, 0, 0);
        z = __builtin_amdgcn_mfma_f32_16x16x32_bf16(A1, B1, z, 0, 0, 0);
#pragma unroll
        for (int qq = 0; qq < 4; ++qq)
            aS[(atom0 + hi * 4 + qq) * C2 + T * 16 + lo] = __float2bfloat16(z[qq]);
    }
}

// Dense stats+store pass (r15 epilogue form: per-qq atom index via magic-mul;
// minimal register footprint, VGPR ~32, occ ~82%).
__global__ __launch_bounds__(256, 4)
void k_edge_dense(const __hip_bfloat16* __restrict__ xb,
                  const __hip_bfloat16* __restrict__ nbrb,
                  const __hip_bfloat16* __restrict__ ballf,
                  const __hip_bfloat16* __restrict__ aS,
                  const int* __restrict__ idxp,
                  float* __restrict__ bn1_slots,
                  __hip_bfloat16* __restrict__ zb) {
    __shared__ float bn_s[256];
    const int t = threadIdx.x;
    const int w = t >> 6, l = t & 63;
    const int lo = l & 15, hi = l >> 4;
    const short* xbS = (const short*)xb;
    const short* nbS = (const short*)nbrb;
    const short* aSS = (const short*)aS;
    const short* bb  = (const short*)ballf;
    short* zbS = (short*)zb;

    bn_s[t] = 0.f;
    __syncthreads();

    const long tile0 = (long)blockIdx.x * 8 + w * 2;   // tiles tile0, tile0+1
    const bf16x8 zz = {0, 0, 0, 0, 0, 0, 0, 0};
    const int off1 = (hi < 2) ? (32 + hi * 8) : 0;

    bf16x8 A[2][4];
    long ebase[2];
#pragma unroll
    for (int g = 0; g < 2; ++g) {
        const long e0 = (tile0 + g) * 16;
        ebase[g] = e0;
        const int j = idxp[e0 + lo];
        const short* xj = xbS + (long)j * FDIM + hi * 8;
        const short* nb = nbS + (e0 + lo) * KP48;
        A[g][0] = *(const bf16x8*)(xj);
        A[g][1] = *(const bf16x8*)(xj + 32);
        A[g][2] = *(const bf16x8*)(nb + hi * 8);
        bf16x8 n1 = *(const bf16x8*)(nb + off1);
        A[g][3] = (hi < 2) ? n1 : zz;
    }

#pragma unroll 2
    for (int P = 0; P < 8; ++P) {
        const short* bp = bb + P * 2048 + l * 8;
        bf16x8 B0 = *(const bf16x8*)(bp);
        bf16x8 B1 = *(const bf16x8*)(bp + 512);
        bf16x8 B2 = *(const bf16x8*)(bp + 1024);
        bf16x8 B3 = *(const bf16x8*)(bp + 1536);
        f32x4 z0 = {0.f, 0.f, 0.f, 0.f}, z1 = {0.f, 0.f, 0.f, 0.f};
        z0 = __builtin_amdgcn_mfma_f32_16x16x32_bf16(A[0][0], B0, z0, 0, 0, 0);
        z1 = __builtin_amdgcn_mfma_f32_16x16x32_bf16(A[1][0], B0, z1, 0, 0, 0);
        z0 = __builtin_amdgcn_mfma_f32_16x16x32_bf16(A[0][1], B1, z0, 0, 0, 0);
        z1 = __builtin_amdgcn_mfma_f32_16x16x32_bf16(A[1][1], B1, z1, 0, 0, 0);
        z0 = __builtin_amdgcn_mfma_f32_16x16x32_bf16(A[0][2], B2, z0, 0, 0, 0);
        z1 = __builtin_amdgcn_mfma_f32_16x16x32_bf16(A[1][2], B2, z1, 0, 0, 0);
        z0 = __builtin_amdgcn_mfma_f32_16x16x32_bf16(A[0][3], B3, z0, 0, 0, 0);
        z1 = __builtin_amdgcn_mfma_f32_16x16x32_bf16(A[1][3], B3, z1, 0, 0, 0);
        const int col = P * 16 + lo;
#pragma unroll
        for (int g = 0; g < 2; ++g) {
            f32x4 z = g ? z1 : z0;
            float s1 = 0.f, s2 = 0.f;
            u16x4 pk;
#pragma unroll
            for (int qq = 0; qq < 4; ++qq) {
                const int n = (int)((ebase[g] + hi * 4 + qq) / 12);
                float av = bf2f((unsigned short)aSS[(long)n * C2 + col]);
                float zp = z[qq] + av;
                pk[qq] = f2bf(zp);
                s1 += zp;
                s2 += zp * zp;
            }
            *(u16x4*)&zbS[(tile0 + g) * 2048 + col * 16 + hi * 4] = pk;
            s1 += __shfl_xor(s1, 16); s2 += __shfl_xor(s2, 16);
            s1 += __shfl_xor(s1, 32); s2 += __shfl_xor(s2, 32);
            if (hi == 0) {
                atomicAdd(&bn_s[col], s1);
                atomicAdd(&bn_s[128 + col], s2);
            }
        }
    }
    __syncthreads();
    atomicAdd(&bn1_slots[(blockIdx.x & 63) * 256 + t], bn_s[t]);
}

__device__ __forceinline__ float act8(const short* f, const short* cc,
                                      float s_f, float h_f, float s_c, float h_c) {
    u16x8 zf = *(const u16x8*)f;
    u16x8 zc = *(const u16x8*)cc;
    float pv = 0.f;
#pragma unroll
    for (int q = 0; q < 8; ++q) {
        float zfh = bf2f(zf[q]) * s_f + h_f;
        float zch = bf2f(zc[q]) * s_c + h_c;
        pv += (1.f / (1.f + __expf(-zfh))) * softplus_f(zch);
    }
    return pv;
}
__device__ __forceinline__ float act4(const short* f, const short* cc,
                                      float s_f, float h_f, float s_c, float h_c) {
    u16x4 zf = *(const u16x4*)f;
    u16x4 zc = *(const u16x4*)cc;
    float pv = 0.f;
#pragma unroll
    for (int q = 0; q < 4; ++q) {
        float zfh = bf2f(zf[q]) * s_f + h_f;
        float zch = bf2f(zc[q]) * s_c + h_c;
        pv += (1.f / (1.f + __expf(-zfh))) * softplus_f(zch);
    }
    return pv;
}

// Streaming apply (grid-stride): in-block BN1 finalize from slots, then each
// thread owns one (atom, col). The atom's 12 rows form <=2 contiguous runs in
// the 16-row tiles; r0 = (12a)&15 is wave-uniform -> branch-uniform loads:
// one 16B u16x8 + one 8B u16x4 (3x u16x4 only when r0==4, misaligned case).
__global__ __launch_bounds__(256, 8)
void k_zapply2(const __hip_bfloat16* __restrict__ zb,
               const float* __restrict__ bn1_layer,
               const float* __restrict__ g1, const float* __restrict__ b1,
               float* __restrict__ sout, float* __restrict__ bn2_slots) {
    __shared__ float bn_s[128];
    __shared__ float sc_s[128], sh_s[128];
    const int t = threadIdx.x;
    if (t < 128) {
        float s1 = 0.f, s2 = 0.f;
        for (int sl = 0; sl < 64; ++sl) {
            s1 += bn1_layer[sl * 256 + t];
            s2 += bn1_layer[sl * 256 + 128 + t];
        }
        const float inv = 1.f / 1200000.f;
        float mu = s1 * inv;
        float var = fmaxf(s2 * inv - mu * mu, 0.f);
        float sc = g1[t] * rsqrtf(var + EPSBN);
        sc_s[t] = sc;
        sh_s[t] = b1[t] - mu * sc;
        bn_s[t] = 0.f;
    }
    __syncthreads();

    const int c = t & 63;
    const float s_f = sc_s[c], h_f = sh_s[c];
    const float s_c = sc_s[64 + c], h_c = sh_s[64 + c];
    const short* zs = (const short*)zb;
    float racc1 = 0.f, racc2 = 0.f;

    for (int grp = blockIdx.x; grp < NATOM / 4; grp += gridDim.x) {
        const int a = grp * 4 + (t >> 6);
        const long e0 = (long)a * 12;
        const long tile = e0 >> 4;
        const int r0 = (int)(e0 & 15);            // wave-uniform: 0,4,8,12
        const short* bA = zs + tile * 2048 + c * 16;
        const short* bB = bA + 64 * 16;
        float pv;
        if (r0 == 0) {
            pv  = act8(bA, bB, s_f, h_f, s_c, h_c);
            pv += act4(bA + 8, bB + 8, s_f, h_f, s_c, h_c);
        } else if (r0 == 4) {
            pv  = act4(bA + 4, bB + 4, s_f, h_f, s_c, h_c);
            pv += act4(bA + 8, bB + 8, s_f, h_f, s_c, h_c);
            pv += act4(bA + 12, bB + 12, s_f, h_f, s_c, h_c);
        } else if (r0 == 8) {
            pv  = act8(bA + 8, bB + 8, s_f, h_f, s_c, h_c);
            pv += act4(bA + 2048, bB + 2048, s_f, h_f, s_c, h_c);
        } else {
            pv  = act4(bA + 12, bB + 12, s_f, h_f, s_c, h_c);
            pv += act8(bA + 2048, bB + 2048, s_f, h_f, s_c, h_c);
        }
        sout[(long)a * FDIM + c] = pv;
        racc1 += pv;
        racc2 += pv * pv;
    }
    atomicAdd(&bn_s[c], racc1);
    atomicAdd(&bn_s[64 + c], racc2);
    __syncthreads();
    if (t < 128)
        atomicAdd(&bn2_slots[(blockIdx.x & 63) * 128 + t], bn_s[t]);
}

// x = softplus(x + bn2(s)) with in-block BN2 finalize from slots; grid-stride.
__global__ __launch_bounds__(256, 8)
void k_x(float* __restrict__ x, __hip_bfloat16* __restrict__ xb,
         const float* __restrict__ s,
         const float* __restrict__ bn2_layer,
         const float* __restrict__ g2, const float* __restrict__ b2) {
    __shared__ float sc_s[64], sh_s[64];
    const int t = threadIdx.x;
    if (t < 64) {
        float s1 = 0.f, s2 = 0.f;
        for (int sl = 0; sl < 64; ++sl) {
            s1 += bn2_layer[sl * 128 + t];
            s2 += bn2_layer[sl * 128 + 64 + t];
        }
        const float inv = 1e-5f;
        float mu = s1 * inv;
        float var = fmaxf(s2 * inv - mu * mu, 0.f);
        float sc = g2[t] * rsqrtf(var + EPSBN);
        sc_s[t] = sc;
        sh_s[t] = b2[t] - mu * sc;
    }
    __syncthreads();
    const long total = (long)NATOM * FDIM;
    const long stride = (long)gridDim.x * 256;
    for (long i = (long)blockIdx.x * 256 + t; i < total; i += stride) {
        int c = (int)(i & 63);
        float v = softplus_f(x[i] + s[i] * sc_s[c] + sh_s[c]);
        x[i] = v;
        xb[i] = __float2bfloat16(v);
    }
}

// ---- fallback path (ws too small for zb): r11 two-pass edge kernel ----
__global__ void k_bnfin(const float* __restrict__ slots, const float* __restrict__ gamma,
                        const float* __restrict__ beta,
                        float* __restrict__ scale, float* __restrict__ shift,
                        float inv_cnt, int nc) {
    int c = threadIdx.x;
    if (c >= nc) return;
    float s1 = 0.f, s2 = 0.f;
    for (int s = 0; s < 64; ++s) {
        s1 += slots[s * 2 * nc + c];
        s2 += slots[s * 2 * nc + nc + c];
    }
    float mu = s1 * inv_cnt;
    float var = fmaxf(s2 * inv_cnt - mu * mu, 0.f);
    float sc = gamma[c] * rsqrtf(var + EPSBN);
    scale[c] = sc;
    shift[c] = beta[c] - mu * sc;
}

template <int APPLY>
__global__ __launch_bounds__(256, 4)
void k_edge(const __hip_bfloat16* __restrict__ xb,
            const __hip_bfloat16* __restrict__ nbrb,
            const __hip_bfloat16* __restrict__ ballf,
            const __hip_bfloat16* __restrict__ aS,
            const int* __restrict__ idxp,
            const float* __restrict__ sc1, const float* __restrict__ sh1,
            float* __restrict__ bn1_slots,
            float* __restrict__ sout, float* __restrict__ bn2_slots) {
    __shared__ float bn_s[256];
    __shared__ float sc_s[128], sh_s[128];

    const int t = threadIdx.x;
    const int w = t >> 6, l = t & 63;
    const int lo = l & 15, hi = l >> 4;
    const bool real = lo < MNBR;
    const int elo = real ? lo : 0;
    const int atom0 = blockIdx.x * 16 + w * 4;
    const short* xbS = (const short*)xb;
    const short* nbS = (const short*)nbrb;
    const short* aSS = (const short*)aS;
    const short* bb  = (const short*)ballf;

    bn_s[t] = 0.f;
    if (APPLY && t < 128) { sc_s[t] = sc1[t]; sh_s[t] = sh1[t]; }
    __syncthreads();

    const bf16x8 zz = {0, 0, 0, 0, 0, 0, 0, 0};
    const int off1 = (hi < 2) ? (32 + hi * 8) : 0;

#pragma unroll 1
    for (int pr = 0; pr < 2; ++pr) {
        const int a0 = atom0 + pr * 2;
        const int a1 = a0 + 1;
        const int j0 = idxp[(long)a0 * MNBR + elo];
        const int j1 = idxp[(long)a1 * MNBR + elo];
        const short* xj0 = xbS + (long)j0 * FDIM + hi * 8;
        const short* xj1 = xbS + (long)j1 * FDIM + hi * 8;
        const short* nb0 = nbS + ((long)a0 * MNBR + elo) * KP48;
        const short* nb1 = nbS + ((long)a1 * MNBR + elo) * KP48;
        bf16x8 A00 = *(const bf16x8*)(xj0);
        bf16x8 A01 = *(const bf16x8*)(xj0 + 32);
        bf16x8 A02 = *(const bf16x8*)(nb0 + hi * 8);
        bf16x8 n03 = *(const bf16x8*)(nb0 + off1);
        bf16x8 A03 = (hi < 2) ? n03 : zz;
        bf16x8 A10 = *(const bf16x8*)(xj1);
        bf16x8 A11 = *(const bf16x8*)(xj1 + 32);
        bf16x8 A12 = *(const bf16x8*)(nb1 + hi * 8);
        bf16x8 n13 = *(const bf16x8*)(nb1 + off1);
        bf16x8 A13 = (hi < 2) ? n13 : zz;

        if (APPLY == 0) {
#pragma unroll 2
            for (int P = 0; P < 8; ++P) {
                const short* bp = bb + P * 2048 + l * 8;
                bf16x8 B0 = *(const bf16x8*)(bp);
                bf16x8 B1 = *(const bf16x8*)(bp + 512);
                bf16x8 B2 = *(const bf16x8*)(bp + 1024);
                bf16x8 B3 = *(const bf16x8*)(bp + 1536);
                float a0v = bf2f((unsigned short)aSS[(long)a0 * C2 + P * 16 + lo]);
                float a1v = bf2f((unsigned short)aSS[(long)a1 * C2 + P * 16 + lo]);
                f32x4 z0 = {0.f, 0.f, 0.f, 0.f}, z1 = {0.f, 0.f, 0.f, 0.f};
                z0 = __builtin_amdgcn_mfma_f32_16x16x32_bf16(A00, B0, z0, 0, 0, 0);
                z1 = __builtin_amdgcn_mfma_f32_16x16x32_bf16(A10, B0, z1, 0, 0, 0);
                z0 = __builtin_amdgcn_mfma_f32_16x16x32_bf16(A01, B1, z0, 0, 0, 0);
                z1 = __builtin_amdgcn_mfma_f32_16x16x32_bf16(A11, B1, z1, 0, 0, 0);
                z0 = __builtin_amdgcn_mfma_f32_16x16x32_bf16(A02, B2, z0, 0, 0, 0);
                z1 = __builtin_amdgcn_mfma_f32_16x16x32_bf16(A12, B2, z1, 0, 0, 0);
                z0 = __builtin_amdgcn_mfma_f32_16x16x32_bf16(A03, B3, z0, 0, 0, 0);
                z1 = __builtin_amdgcn_mfma_f32_16x16x32_bf16(A13, B3, z1, 0, 0, 0);
#pragma unroll
                for (int g = 0; g < 2; ++g) {
                    f32x4 z = g ? z1 : z0;
                    float av = g ? a1v : a0v;
                    float sz = z[0] + z[1] + z[2] + z[3];
                    float szz = z[0] * z[0] + z[1] * z[1] + z[2] * z[2] + z[3] * z[3];
                    float s1 = sz + 4.f * av;
                    float s2 = szz + 2.f * av * sz + 4.f * av * av;
                    if (hi == 3) { s1 = 0.f; s2 = 0.f; }
                    s1 += __shfl_xor(s1, 16); s2 += __shfl_xor(s2, 16);
                    s1 += __shfl_xor(s1, 32); s2 += __shfl_xor(s2, 32);
                    if (hi == 0) {
                        atomicAdd(&bn_s[P * 16 + lo], s1);
                        atomicAdd(&bn_s[128 + P * 16 + lo], s2);
                    }
                }
            }
        } else {
#pragma unroll 1
            for (int P = 0; P < 4; ++P) {
                const short* bpf = bb + P * 2048 + l * 8;
                const short* bpc = bb + (P + 4) * 2048 + l * 8;
                bf16x8 Bf0 = *(const bf16x8*)(bpf);
                bf16x8 Bf1 = *(const bf16x8*)(bpf + 512);
                bf16x8 Bf2 = *(const bf16x8*)(bpf + 1024);
                bf16x8 Bf3 = *(const bf16x8*)(bpf + 1536);
                bf16x8 Bc0 = *(const bf16x8*)(bpc);
                bf16x8 Bc1 = *(const bf16x8*)(bpc + 512);
                bf16x8 Bc2 = *(const bf16x8*)(bpc + 1024);
                bf16x8 Bc3 = *(const bf16x8*)(bpc + 1536);
                const int c = P * 16 + lo;
                const float s_f = sc_s[c], h_f = sh_s[c];
                const float s_c = sc_s[64 + c], h_c = sh_s[64 + c];
                float hv0f = bf2f((unsigned short)aSS[(long)a0 * C2 + c]) * s_f + h_f;
                float hv0c = bf2f((unsigned short)aSS[(long)a0 * C2 + 64 + c]) * s_c + h_c;
                float hv1f = bf2f((unsigned short)aSS[(long)a1 * C2 + c]) * s_f + h_f;
                float hv1c = bf2f((unsigned short)aSS[(long)a1 * C2 + 64 + c]) * s_c + h_c;
                f32x4 zf0 = {0.f, 0.f, 0.f, 0.f}, zc0 = {0.f, 0.f, 0.f, 0.f};
                f32x4 zf1 = {0.f, 0.f, 0.f, 0.f}, zc1 = {0.f, 0.f, 0.f, 0.f};
                zf0 = __builtin_amdgcn_mfma_f32_16x16x32_bf16(A00, Bf0, zf0, 0, 0, 0);
                zc0 = __builtin_amdgcn_mfma_f32_16x16x32_bf16(A00, Bc0, zc0, 0, 0, 0);
                zf1 = __builtin_amdgcn_mfma_f32_16x16x32_bf16(A10, Bf0, zf1, 0, 0, 0);
                zc1 = __builtin_amdgcn_mfma_f32_16x16x32_bf16(A10, Bc0, zc1, 0, 0, 0);
                zf0 = __builtin_amdgcn_mfma_f32_16x16x32_bf16(A01, Bf1, zf0, 0, 0, 0);
                zc0 = __builtin_amdgcn_mfma_f32_16x16x32_bf16(A01, Bc1, zc0, 0, 0, 0);
                zf1 = __builtin_amdgcn_mfma_f32_16x16x32_bf16(A11, Bf1, zf1, 0, 0, 0);
                zc1 = __builtin_amdgcn_mfma_f32_16x16x32_bf16(A11, Bc1, zc1, 0, 0, 0);
                zf0 = __builtin_amdgcn_mfma_f32_16x16x32_bf16(A02, Bf2, zf0, 0, 0, 0);
                zc0 = __builtin_amdgcn_mfma_f32_16x16x32_bf16(A02, Bc2, zc0, 0, 0, 0);
                zf1 = __builtin_amdgcn_mfma_f32_16x16x32_bf16(A12, Bf2, zf1, 0, 0, 0);
                zc1 = __builtin_amdgcn_mfma_f32_16x16x32_bf16(A12, Bc2, zc1, 0, 0, 0);
                zf0 = __builtin_amdgcn_mfma_f32_16x16x32_bf16(A03, Bf3, zf0, 0, 0, 0);
                zc0 = __builtin_amdgcn_mfma_f32_16x16x32_bf16(A03, Bc3, zc0, 0, 0, 0);
                zf1 = __builtin_amdgcn_mfma_f32_16x16x32_bf16(A13, Bf3, zf1, 0, 0, 0);
                zc1 = __builtin_amdgcn_mfma_f32_16x16x32_bf16(A13, Bc3, zc1, 0, 0, 0);
#pragma unroll
                for (int g = 0; g < 2; ++g) {
                    f32x4 zf = g ? zf1 : zf0;
                    f32x4 zc = g ? zc1 : zc0;
                    float hvf = g ? hv1f : hv0f;
                    float hvc = g ? hv1c : hv0c;
                    float pvsum = 0.f;
#pragma unroll
                    for (int qq = 0; qq < 4; ++qq) {
                        float zfh = zf[qq] * s_f + hvf;
                        float zch = zc[qq] * s_c + hvc;
                        float filt = 1.f / (1.f + __expf(-zfh));
                        pvsum += filt * softplus_f(zch);
                    }
                    if (hi == 3) pvsum = 0.f;
                    pvsum += __shfl_xor(pvsum, 16);
                    pvsum += __shfl_xor(pvsum, 32);
                    if (hi == 0) {
                        sout[(long)(g ? a1 : a0) * FDIM + c] = pvsum;
                        atomicAdd(&bn_s[c], pvsum);
                        atomicAdd(&bn_s[64 + c], pvsum * pvsum);
                    }
                }
            }
        }
    }

    __syncthreads();
    if (APPLY == 0) {
        atomicAdd(&bn1_slots[(blockIdx.x & 63) * 256 + t], bn_s[t]);
    } else {
        if (t < 128)
            atomicAdd(&bn2_slots[(blockIdx.x & 63) * 128 + t], bn_s[t]);
    }
}

__global__ void k_pool(const float* __restrict__ x, const int* __restrict__ seg,
                       float* __restrict__ cry, float* __restrict__ cnt) {
    long i = (long)blockIdx.x * 256 + threadIdx.x;
    if (i >= (long)NATOM * FDIM) return;
    int n = (int)(i >> 6), c = (int)(i & 63);
    int cr = seg[n];
    atomicAdd(&cry[(long)cr * FDIM + c], x[i]);
    if (c == 0) atomicAdd(&cnt[cr], 1.f);
}

__global__ __launch_bounds__(256)
void k_head(const float* __restrict__ cry, const float* __restrict__ cnt,
            const float* __restrict__ fw, const float* __restrict__ fb,
            const float* __restrict__ hw, const float* __restrict__ hb,
            const float* __restrict__ ow, const float* __restrict__ ob,
            float* __restrict__ out) {
    __shared__ float cs[64], h1[128], red[256];
    int t = threadIdx.x, cr = blockIdx.x;
    if (t < 64) cs[t] = cry[(long)cr * 64 + t] / fmaxf(cnt[cr], 1.f);
    __syncthreads();
    if (t < 128) {
        float a = fb[t];
        for (int k = 0; k < 64; ++k) a += cs[k] * fw[k * 128 + t];
        h1[t] = fmaxf(a, 0.f);
    }
    __syncthreads();
    float a = hb[t];
    for (int k = 0; k < 128; ++k) a += h1[k] * hw[k * 256 + t];
    red[t] = a * ow[t];
    __syncthreads();
    for (int off = 128; off > 0; off >>= 1) {
        if (t < off) red[t] += red[t + off];
        __syncthreads();
    }
    if (t == 0) out[cr] = red[0] + ob[0];
}

extern "C" void kernel_launch(void* const* d_in, const int* in_sizes, int n_in,
                              void* d_out, int out_size, void* d_ws, size_t ws_size,
                              hipStream_t stream) {
    const float* atom_fea = (const float*)d_in[0];
    const float* nbr_fea  = (const float*)d_in[1];
    const int*   nbr_idx  = (const int*)d_in[2];
    const int*   seg      = (const int*)d_in[3];
    const float* emb_w    = (const float*)d_in[4];
    const float* emb_b    = (const float*)d_in[5];
    const float* conv_w   = (const float*)d_in[6];
    const float* bn1_g    = (const float*)d_in[8];
    const float* bn1_b    = (const float*)d_in[9];
    const float* bn2_g    = (const float*)d_in[10];
    const float* bn2_b    = (const float*)d_in[11];
    const float* fc_w     = (const float*)d_in[12];
    const float* fc_b     = (const float*)d_in[13];
    const float* head_w   = (const float*)d_in[14];
    const float* head_b   = (const float*)d_in[15];
    const float* out_w    = (const float*)d_in[16];
    const float* out_b    = (const float*)d_in[17];
    float* out = (float*)d_out;

    float* ws = (float*)d_ws;
    float* x = ws + X_OFF;
    __hip_bfloat16* xb     = (__hip_bfloat16*)(ws + XB_OFF);
    float* s = ws + S_OFF;
    __hip_bfloat16* nbrb   = (__hip_bfloat16*)(ws + NBRB_OFF);
    __hip_bfloat16* aS     = (__hip_bfloat16*)(ws + AS_OFF);
    __hip_bfloat16* ballf  = (__hip_bfloat16*)(ws + BALL_OFF);
    __hip_bfloat16* ballfS = (__hip_bfloat16*)(ws + BALLS_OFF);
    float* bn1s = ws + BN1S_OFF;
    float* bn2s = ws + BN2S_OFF;
    float* cry = ws + CRY_OFF;
    float* cnt = ws + CNT_OFF;
    float* sc1 = ws + SC1_OFF;
    float* sh1 = ws + SH1_OFF;
    __hip_bfloat16* zb = (__hip_bfloat16*)(ws + ZB_OFF);
    const bool fused = (ws_size >= (size_t)WS_NEED_FUSED);

    k_zero<<<(int)((ZERO_CNT + 255) / 256), 256, 0, stream>>>(ws + ZERO_OFF, ZERO_CNT);
    k_nbrcvt<<<(int)(((long)NEDGE * 6 + 255) / 256), 256, 0, stream>>>(nbr_fea, nbrb);
    k_embed<<<NATOM / 16, 256, 0, stream>>>(atom_fea, emb_w, emb_b, x, xb);

    for (int i = 0; i < 3; ++i) {
        const float* cw = conv_w + (long)i * 169 * C2;
        float* bn1L = bn1s + (long)i * 16384;
        float* bn2L = bn2s + (long)i * 8192;
        k_bcvt<<<96, 256, 0, stream>>>(cw, ballf, ballfS);
        k_lin<<<1563, 256, 0, stream>>>(xb, ballfS, aS);
        if (fused) {
            k_edge_dense<<<9375, 256, 0, stream>>>(xb, nbrb, ballf, aS, nbr_idx, bn1L, zb);
            k_zapply2<<<2048, 256, 0, stream>>>(zb, bn1L, bn1_g + i * C2, bn1_b + i * C2,
                                                s, bn2L);
        } else {
            k_edge<0><<<NATOM / 16, 256, 0, stream>>>(xb, nbrb, ballf, aS, nbr_idx,
                                                      nullptr, nullptr, bn1L, nullptr, nullptr);
            k_bnfin<<<1, 128, 0, stream>>>(bn1L, bn1_g + i * C2, bn1_b + i * C2,
                                           sc1, sh1, 1.f / 1200000.f, 128);
            k_edge<1><<<NATOM / 16, 256, 0, stream>>>(xb, nbrb, ballf, aS, nbr_idx,
                                                      sc1, sh1, nullptr, s, bn2L);
        }
        k_x<<<2048, 256, 0, stream>>>(x, xb, s, bn2L, bn2_g + i * 64, bn2_b + i * 64);
    }

    k_pool<<<(NATOM * FDIM) / 256, 256, 0, stream>>>(x, seg, cry, cnt);
    k_head<<<2000, 256, 0, stream>>>(cry, cnt, fc_w, fc_b, head_w, head_b, out_w, out_b, out);
}

// Round 18
// 1123.951 us; speedup vs baseline: 1.5117x; 1.0621x over previous
//
#include <hip/hip_runtime.h>
#include <hip/hip_bf16.h>

#define NATOM 100000
#define MNBR  12
#define FDIM  64
#define BDIM  41
#define C2    128
#define EPSBN 1e-5f
#define NEDGE (NATOM * MNBR)   // 1,200,000
#define KP48  48               // nbr packed width (41 real + 7 zero), 96B rows
#define NFRAG  16384           // edge B frag-linear: 8T * 4s * 64l * 8e (rows 64..168)
#define NFRAGS 8192            // self B frag-linear: 8T * 2s * 64l * 8e (rows 0..63)

typedef __attribute__((ext_vector_type(8))) short bf16x8;
typedef __attribute__((ext_vector_type(8))) unsigned short u16x8;
typedef __attribute__((ext_vector_type(4))) unsigned short u16x4;
typedef __attribute__((ext_vector_type(4))) float f32x4;

// ---- ws layout (float units) ----
#define X_OFF    0L            // x: N*64 f32 (master)
#define XB_OFF   6400000L      // xb: N*64 bf16
#define S_OFF    9600000L      // nbr_sumed: N*64 f32
#define NBRB_OFF 16000000L     // nbr bf16 packed 48-wide: 1.2M*48 bf16 (28.8M floats)
#define AS_OFF   54400000L     // a = x@W_self: N*128 bf16 (6.4M floats)
#define BALL_OFF 60800000L     // edge B frag bf16: 16384 elems (8192 floats)
#define BALLS_OFF 60808192L    // self B frag bf16: 8192 elems (4096 floats)
#define BN1S_OFF 60812288L     // 3 layers * 64 slots * 256 = 49152
#define BN2S_OFF 60861440L     // 3 layers * 64 slots * 128 = 24576
#define CRY_OFF  60886016L     // 2000*64
#define CNT_OFF  61014016L     // 2000
#define SC1_OFF  61016016L     // 128 (fallback only)
#define SH1_OFF  61016144L     // 128 (fallback only)
#define ZB_OFF   61016272L     // z bf16: 75000 tiles * 2048 shorts (76.8M floats)
#define WS_NEED_FUSED ((ZB_OFF + 76800000L) * 4L)
#define ZERO_OFF BN1S_OFF
#define ZERO_CNT 203728L       // slots(49152+24576) + cry(128000) + cnt(2000)

__device__ __forceinline__ float bf2f(unsigned short u) {
    return __uint_as_float(((unsigned)u) << 16);
}
__device__ __forceinline__ unsigned short f2bf(float f) {
    __hip_bfloat16 h = __float2bfloat16(f);
    return *(unsigned short*)&h;
}
__device__ __forceinline__ float softplus_f(float v) {
    return fmaxf(v, 0.f) + __logf(1.f + __expf(-fabsf(v)));
}

__global__ void k_zero(float* __restrict__ p, long cnt) {
    long i = (long)blockIdx.x * 256 + threadIdx.x;
    if (i < cnt) p[i] = 0.f;
}

// nbr_fea f32 [1.2M][41] -> bf16 [1.2M][48] zero-padded; short8-vectorized writes
__global__ void k_nbrcvt(const float* __restrict__ nbr, __hip_bfloat16* __restrict__ outb) {
    long i = (long)blockIdx.x * 256 + threadIdx.x;
    if (i >= (long)NEDGE * 6) return;
    long e = i / 6;
    int c = (int)(i - e * 6);
    const float* src = nbr + e * BDIM + c * 8;
    bf16x8 v;
#pragma unroll
    for (int j = 0; j < 8; ++j) {
        int k = c * 8 + j;
        float f = (k < BDIM) ? src[j] : 0.f;
        v[j] = (short)f2bf(f);
    }
    *(bf16x8*)((short*)outb + e * KP48 + c * 8) = v;
}

// Fragment-linear B for both GEMMs.
__global__ void k_bcvt(const float* __restrict__ cw, __hip_bfloat16* __restrict__ ballf,
                       __hip_bfloat16* __restrict__ ballfS) {
    int i = blockIdx.x * 256 + threadIdx.x;
    if (i < NFRAG) {
        int T = i / 2048, r = i - T * 2048;
        int lidx = (r >> 3) & 63, e = i & 7;
        int s4 = r >> 9;
        int lo = lidx & 15, hi = lidx >> 4;
        int krow = 64 + s4 * 32 + hi * 8 + e;
        float v = (krow < 169) ? cw[krow * C2 + T * 16 + lo] : 0.f;
        ballf[i] = __float2bfloat16(v);
    } else if (i < NFRAG + NFRAGS) {
        int i2 = i - NFRAG;
        int T = i2 / 1024, r = i2 - T * 1024;
        int lidx = (r >> 3) & 63, e = i2 & 7;
        int s = r >> 9;
        int lo = lidx & 15, hi = lidx >> 4;
        int krow = s * 32 + hi * 8 + e;   // 0..63
        ballfS[i2] = __float2bfloat16(cw[krow * C2 + T * 16 + lo]);
    }
}

__global__ __launch_bounds__(256)
void k_embed(const float* __restrict__ af, const float* __restrict__ ew,
             const float* __restrict__ eb, float* __restrict__ x,
             __hip_bfloat16* __restrict__ xb) {
    int t = threadIdx.x;
    int c = t & 63, ag = t >> 6;
    long n0 = (long)blockIdx.x * 16 + ag * 4;
    float acc[4] = {0.f, 0.f, 0.f, 0.f};
    for (int k4 = 0; k4 < 23; ++k4) {
        float w0 = ew[(4 * k4 + 0) * FDIM + c];
        float w1 = ew[(4 * k4 + 1) * FDIM + c];
        float w2 = ew[(4 * k4 + 2) * FDIM + c];
        float w3 = ew[(4 * k4 + 3) * FDIM + c];
#pragma unroll
        for (int a = 0; a < 4; ++a) {
            const float4* ar = (const float4*)(af + (n0 + a) * 92);
            float4 v = ar[k4];
            acc[a] += v.x * w0 + v.y * w1 + v.z * w2 + v.w * w3;
        }
    }
    float b = eb[c];
#pragma unroll
    for (int a = 0; a < 4; ++a) {
        float v = acc[a] + b;
        x[(n0 + a) * FDIM + c] = v;
        xb[(n0 + a) * FDIM + c] = __float2bfloat16(v);
    }
}

// aS = xb @ W_self via MFMA: one 16-atom tile per wave (A rows = atoms).
__global__ __launch_bounds__(256, 8)
void k_lin(const __hip_bfloat16* __restrict__ xb, const __hip_bfloat16* __restrict__ ballfS,
           __hip_bfloat16* __restrict__ aS) {
    int t = threadIdx.x, w = t >> 6, l = t & 63;
    int lo = l & 15, hi = l >> 4;
    long atom0 = ((long)blockIdx.x * 4 + w) * 16;
    if (atom0 >= NATOM) return;
    const short* xs = (const short*)xb + (atom0 + lo) * FDIM + hi * 8;
    bf16x8 A0 = *(const bf16x8*)(xs);
    bf16x8 A1 = *(const bf16x8*)(xs + 32);
    const short* bS = (const short*)ballfS;
#pragma unroll
    for (int T = 0; T < 8; ++T) {
        bf16x8 B0 = *(const bf16x8*)(bS + T * 1024 + l * 8);
        bf16x8 B1 = *(const bf16x8*)(bS + T * 1024 + 512 + l * 8);
        f32x4 z = {0.f, 0.f, 0.f, 0.f};
        z = __builtin_amdgcn_mfma_f32_16x16x32_bf16(A0, B0, z, 0, 0, 0);
        z = __builtin_amdgcn_mfma_f32_16x16x32_bf16(A1, B1, z, 0, 0, 0);
#pragma unroll
        for (int qq = 0; qq < 4; ++qq)
            aS[(atom0 + hi * 4 + qq) * C2 + T * 16 + lo] = __float2bfloat16(z[qq]);
    }
}

// Dense stats+store pass. Per-P epilogue: the two tiles (g=0,1) contribute to
// the SAME column (col = P*16+lo), so their partial sums are merged in
// registers first -> ONE shfl chain + ONE atomic pair per P (was two).
__global__ __launch_bounds__(256, 4)
void k_edge_dense(const __hip_bfloat16* __restrict__ xb,
                  const __hip_bfloat16* __restrict__ nbrb,
                  const __hip_bfloat16* __restrict__ ballf,
                  const __hip_bfloat16* __restrict__ aS,
                  const int* __restrict__ idxp,
                  float* __restrict__ bn1_slots,
                  __hip_bfloat16* __restrict__ zb) {
    __shared__ float bn_s[256];
    const int t = threadIdx.x;
    const int w = t >> 6, l = t & 63;
    const int lo = l & 15, hi = l >> 4;
    const short* xbS = (const short*)xb;
    const short* nbS = (const short*)nbrb;
    const short* aSS = (const short*)aS;
    const short* bb  = (const short*)ballf;
    short* zbS = (short*)zb;

    bn_s[t] = 0.f;
    __syncthreads();

    const long tile0 = (long)blockIdx.x * 8 + w * 2;   // tiles tile0, tile0+1
    const bf16x8 zz = {0, 0, 0, 0, 0, 0, 0, 0};
    const int off1 = (hi < 2) ? (32 + hi * 8) : 0;

    bf16x8 A[2][4];
    long ebase[2];
#pragma unroll
    for (int g = 0; g < 2; ++g) {
        const long e0 = (tile0 + g) * 16;
        ebase[g] = e0;
        const int j = idxp[e0 + lo];
        const short* xj = xbS + (long)j * FDIM + hi * 8;
        const short* nb = nbS + (e0 + lo) * KP48;
        A[g][0] = *(const bf16x8*)(xj);
        A[g][1] = *(const bf16x8*)(xj + 32);
        A[g][2] = *(const bf16x8*)(nb + hi * 8);
        bf16x8 n1 = *(const bf16x8*)(nb + off1);
        A[g][3] = (hi < 2) ? n1 : zz;
    }

#pragma unroll 2
    for (int P = 0; P < 8; ++P) {
        const short* bp = bb + P * 2048 + l * 8;
        bf16x8 B0 = *(const bf16x8*)(bp);
        bf16x8 B1 = *(const bf16x8*)(bp + 512);
        bf16x8 B2 = *(const bf16x8*)(bp + 1024);
        bf16x8 B3 = *(const bf16x8*)(bp + 1536);
        f32x4 z0 = {0.f, 0.f, 0.f, 0.f}, z1 = {0.f, 0.f, 0.f, 0.f};
        z0 = __builtin_amdgcn_mfma_f32_16x16x32_bf16(A[0][0], B0, z0, 0, 0, 0);
        z1 = __builtin_amdgcn_mfma_f32_16x16x32_bf16(A[1][0], B0, z1, 0, 0, 0);
        z0 = __builtin_amdgcn_mfma_f32_16x16x32_bf16(A[0][1], B1, z0, 0, 0, 0);
        z1 = __builtin_amdgcn_mfma_f32_16x16x32_bf16(A[1][1], B1, z1, 0, 0, 0);
        z0 = __builtin_amdgcn_mfma_f32_16x16x32_bf16(A[0][2], B2, z0, 0, 0, 0);
        z1 = __builtin_amdgcn_mfma_f32_16x16x32_bf16(A[1][2], B2, z1, 0, 0, 0);
        z0 = __builtin_amdgcn_mfma_f32_16x16x32_bf16(A[0][3], B3, z0, 0, 0, 0);
        z1 = __builtin_amdgcn_mfma_f32_16x16x32_bf16(A[1][3], B3, z1, 0, 0, 0);
        const int col = P * 16 + lo;
        float s1 = 0.f, s2 = 0.f;
#pragma unroll
        for (int g = 0; g < 2; ++g) {
            f32x4 z = g ? z1 : z0;
            u16x4 pk;
#pragma unroll
            for (int qq = 0; qq < 4; ++qq) {
                const int n = (int)((ebase[g] + hi * 4 + qq) / 12);
                float av = bf2f((unsigned short)aSS[(long)n * C2 + col]);
                float zp = z[qq] + av;
                pk[qq] = f2bf(zp);
                s1 += zp;
                s2 += zp * zp;
            }
            *(u16x4*)&zbS[(tile0 + g) * 2048 + col * 16 + hi * 4] = pk;
        }
        s1 += __shfl_xor(s1, 16); s2 += __shfl_xor(s2, 16);
        s1 += __shfl_xor(s1, 32); s2 += __shfl_xor(s2, 32);
        if (hi == 0) {
            atomicAdd(&bn_s[col], s1);
            atomicAdd(&bn_s[128 + col], s2);
        }
    }
    __syncthreads();
    atomicAdd(&bn1_slots[(blockIdx.x & 63) * 256 + t], bn_s[t]);
}

__device__ __forceinline__ float act8(const short* f, const short* cc,
                                      float s_f, float h_f, float s_c, float h_c) {
    u16x8 zf = *(const u16x8*)f;
    u16x8 zc = *(const u16x8*)cc;
    float pv = 0.f;
#pragma unroll
    for (int q = 0; q < 8; ++q) {
        float zfh = bf2f(zf[q]) * s_f + h_f;
        float zch = bf2f(zc[q]) * s_c + h_c;
        pv += (1.f / (1.f + __expf(-zfh))) * softplus_f(zch);
    }
    return pv;
}
__device__ __forceinline__ float act4(const short* f, const short* cc,
                                      float s_f, float h_f, float s_c, float h_c) {
    u16x4 zf = *(const u16x4*)f;
    u16x4 zc = *(const u16x4*)cc;
    float pv = 0.f;
#pragma unroll
    for (int q = 0; q < 4; ++q) {
        float zfh = bf2f(zf[q]) * s_f + h_f;
        float zch = bf2f(zc[q]) * s_c + h_c;
        pv += (1.f / (1.f + __expf(-zfh))) * softplus_f(zch);
    }
    return pv;
}

// Streaming apply (grid-stride): in-block BN1 finalize from slots, then each
// thread owns one (atom, col); branch-uniform 16B/8B loads.
__global__ __launch_bounds__(256, 8)
void k_zapply2(const __hip_bfloat16* __restrict__ zb,
               const float* __restrict__ bn1_layer,
               const float* __restrict__ g1, const float* __restrict__ b1,
               float* __restrict__ sout, float* __restrict__ bn2_slots) {
    __shared__ float bn_s[128];
    __shared__ float sc_s[128], sh_s[128];
    const int t = threadIdx.x;
    if (t < 128) {
        float s1 = 0.f, s2 = 0.f;
        for (int sl = 0; sl < 64; ++sl) {
            s1 += bn1_layer[sl * 256 + t];
            s2 += bn1_layer[sl * 256 + 128 + t];
        }
        const float inv = 1.f / 1200000.f;
        float mu = s1 * inv;
        float var = fmaxf(s2 * inv - mu * mu, 0.f);
        float sc = g1[t] * rsqrtf(var + EPSBN);
        sc_s[t] = sc;
        sh_s[t] = b1[t] - mu * sc;
        bn_s[t] = 0.f;
    }
    __syncthreads();

    const int c = t & 63;
    const float s_f = sc_s[c], h_f = sh_s[c];
    const float s_c = sc_s[64 + c], h_c = sh_s[64 + c];
    const short* zs = (const short*)zb;
    float racc1 = 0.f, racc2 = 0.f;

    for (int grp = blockIdx.x; grp < NATOM / 4; grp += gridDim.x) {
        const int a = grp * 4 + (t >> 6);
        const long e0 = (long)a * 12;
        const long tile = e0 >> 4;
        const int r0 = (int)(e0 & 15);            // wave-uniform: 0,4,8,12
        const short* bA = zs + tile * 2048 + c * 16;
        const short* bB = bA + 64 * 16;
        float pv;
        if (r0 == 0) {
            pv  = act8(bA, bB, s_f, h_f, s_c, h_c);
            pv += act4(bA + 8, bB + 8, s_f, h_f, s_c, h_c);
        } else if (r0 == 4) {
            pv  = act4(bA + 4, bB + 4, s_f, h_f, s_c, h_c);
            pv += act4(bA + 8, bB + 8, s_f, h_f, s_c, h_c);
            pv += act4(bA + 12, bB + 12, s_f, h_f, s_c, h_c);
        } else if (r0 == 8) {
            pv  = act8(bA + 8, bB + 8, s_f, h_f, s_c, h_c);
            pv += act4(bA + 2048, bB + 2048, s_f, h_f, s_c, h_c);
        } else {
            pv  = act4(bA + 12, bB + 12, s_f, h_f, s_c, h_c);
            pv += act8(bA + 2048, bB + 2048, s_f, h_f, s_c, h_c);
        }
        sout[(long)a * FDIM + c] = pv;
        racc1 += pv;
        racc2 += pv * pv;
    }
    atomicAdd(&bn_s[c], racc1);
    atomicAdd(&bn_s[64 + c], racc2);
    __syncthreads();
    if (t < 128)
        atomicAdd(&bn2_slots[(blockIdx.x & 63) * 128 + t], bn_s[t]);
}

// x = softplus(x + bn2(s)) with in-block BN2 finalize from slots; grid-stride.
__global__ __launch_bounds__(256, 8)
void k_x(float* __restrict__ x, __hip_bfloat16* __restrict__ xb,
         const float* __restrict__ s,
         const float* __restrict__ bn2_layer,
         const float* __restrict__ g2, const float* __restrict__ b2) {
    __shared__ float sc_s[64], sh_s[64];
    const int t = threadIdx.x;
    if (t < 64) {
        float s1 = 0.f, s2 = 0.f;
        for (int sl = 0; sl < 64; ++sl) {
            s1 += bn2_layer[sl * 128 + t];
            s2 += bn2_layer[sl * 128 + 64 + t];
        }
        const float inv = 1e-5f;
        float mu = s1 * inv;
        float var = fmaxf(s2 * inv - mu * mu, 0.f);
        float sc = g2[t] * rsqrtf(var + EPSBN);
        sc_s[t] = sc;
        sh_s[t] = b2[t] - mu * sc;
    }
    __syncthreads();
    const long total = (long)NATOM * FDIM;
    const long stride = (long)gridDim.x * 256;
    for (long i = (long)blockIdx.x * 256 + t; i < total; i += stride) {
        int c = (int)(i & 63);
        float v = softplus_f(x[i] + s[i] * sc_s[c] + sh_s[c]);
        x[i] = v;
        xb[i] = __float2bfloat16(v);
    }
}

// ---- fallback path (ws too small for zb): r11 two-pass edge kernel ----
__global__ void k_bnfin(const float* __restrict__ slots, const float* __restrict__ gamma,
                        const float* __restrict__ beta,
                        float* __restrict__ scale, float* __restrict__ shift,
                        float inv_cnt, int nc) {
    int c = threadIdx.x;
    if (c >= nc) return;
    float s1 = 0.f, s2 = 0.f;
    for (int s = 0; s < 64; ++s) {
        s1 += slots[s * 2 * nc + c];
        s2 += slots[s * 2 * nc + nc + c];
    }
    float mu = s1 * inv_cnt;
    float var = fmaxf(s2 * inv_cnt - mu * mu, 0.f);
    float sc = gamma[c] * rsqrtf(var + EPSBN);
    scale[c] = sc;
    shift[c] = beta[c] - mu * sc;
}

template <int APPLY>
__global__ __launch_bounds__(256, 4)
void k_edge(const __hip_bfloat16* __restrict__ xb,
            const __hip_bfloat16* __restrict__ nbrb,
            const __hip_bfloat16* __restrict__ ballf,
            const __hip_bfloat16* __restrict__ aS,
            const int* __restrict__ idxp,
            const float* __restrict__ sc1, const float* __restrict__ sh1,
            float* __restrict__ bn1_slots,
            float* __restrict__ sout, float* __restrict__ bn2_slots) {
    __shared__ float bn_s[256];
    __shared__ float sc_s[128], sh_s[128];

    const int t = threadIdx.x;
    const int w = t >> 6, l = t & 63;
    const int lo = l & 15, hi = l >> 4;
    const bool real = lo < MNBR;
    const int elo = real ? lo : 0;
    const int atom0 = blockIdx.x * 16 + w * 4;
    const short* xbS = (const short*)xb;
    const short* nbS = (const short*)nbrb;
    const short* aSS = (const short*)aS;
    const short* bb  = (const short*)ballf;

    bn_s[t] = 0.f;
    if (APPLY && t < 128) { sc_s[t] = sc1[t]; sh_s[t] = sh1[t]; }
    __syncthreads();

    const bf16x8 zz = {0, 0, 0, 0, 0, 0, 0, 0};
    const int off1 = (hi < 2) ? (32 + hi * 8) : 0;

#pragma unroll 1
    for (int pr = 0; pr < 2; ++pr) {
        const int a0 = atom0 + pr * 2;
        const int a1 = a0 + 1;
        const int j0 = idxp[(long)a0 * MNBR + elo];
        const int j1 = idxp[(long)a1 * MNBR + elo];
        const short* xj0 = xbS + (long)j0 * FDIM + hi * 8;
        const short* xj1 = xbS + (long)j1 * FDIM + hi * 8;
        const short* nb0 = nbS + ((long)a0 * MNBR + elo) * KP48;
        const short* nb1 = nbS + ((long)a1 * MNBR + elo) * KP48;
        bf16x8 A00 = *(const bf16x8*)(xj0);
        bf16x8 A01 = *(const bf16x8*)(xj0 + 32);
        bf16x8 A02 = *(const bf16x8*)(nb0 + hi * 8);
        bf16x8 n03 = *(const bf16x8*)(nb0 + off1);
        bf16x8 A03 = (hi < 2) ? n03 : zz;
        bf16x8 A10 = *(const bf16x8*)(xj1);
        bf16x8 A11 = *(const bf16x8*)(xj1 + 32);
        bf16x8 A12 = *(const bf16x8*)(nb1 + hi * 8);
        bf16x8 n13 = *(const bf16x8*)(nb1 + off1);
        bf16x8 A13 = (hi < 2) ? n13 : zz;

        if (APPLY == 0) {
#pragma unroll 2
            for (int P = 0; P < 8; ++P) {
                const short* bp = bb + P * 2048 + l * 8;
                bf16x8 B0 = *(const bf16x8*)(bp);
                bf16x8 B1 = *(const bf16x8*)(bp + 512);
                bf16x8 B2 = *(const bf16x8*)(bp + 1024);
                bf16x8 B3 = *(const bf16x8*)(bp + 1536);
                float a0v = bf2f((unsigned short)aSS[(long)a0 * C2 + P * 16 + lo]);
                float a1v = bf2f((unsigned short)aSS[(long)a1 * C2 + P * 16 + lo]);
                f32x4 z0 = {0.f, 0.f, 0.f, 0.f}, z1 = {0.f, 0.f, 0.f, 0.f};
                z0 = __builtin_amdgcn_mfma_f32_16x16x32_bf16(A00, B0, z0, 0, 0, 0);
                z1 = __builtin_amdgcn_mfma_f32_16x16x32_bf16(A10, B0, z1, 0, 0, 0);
                z0 = __builtin_amdgcn_mfma_f32_16x16x32_bf16(A01, B1, z0, 0, 0, 0);
                z1 = __builtin_amdgcn_mfma_f32_16x16x32_bf16(A11, B1, z1, 0, 0, 0);
                z0 = __builtin_amdgcn_mfma_f32_16x16x32_bf16(A02, B2, z0, 0, 0, 0);
                z1 = __builtin_amdgcn_mfma_f32_16x16x32_bf16(A12, B2, z1, 0, 0, 0);
                z0 = __builtin_amdgcn_mfma_f32_16x16x32_bf16(A03, B3, z0, 0, 0, 0);
                z1 = __builtin_amdgcn_mfma_f32_16x16x32_bf16(A13, B3, z1, 0, 0, 0);
#pragma unroll
                for (int g = 0; g < 2; ++g) {
                    f32x4 z = g ? z1 : z0;
                    float av = g ? a1v : a0v;
                    float sz = z[0] + z[1] + z[2] + z[3];
                    float szz = z[0] * z[0] + z[1] * z[1] + z[2] * z[2] + z[3] * z[3];
                    float s1 = sz + 4.f * av;
                    float s2 = szz + 2.f * av * sz + 4.f * av * av;
                    if (hi == 3) { s1 = 0.f; s2 = 0.f; }
                    s1 += __shfl_xor(s1, 16); s2 += __shfl_xor(s2, 16);
                    s1 += __shfl_xor(s1, 32); s2 += __shfl_xor(s2, 32);
                    if (hi == 0) {
                        atomicAdd(&bn_s[P * 16 + lo], s1);
                        atomicAdd(&bn_s[128 + P * 16 + lo], s2);
                    }
                }
            }
        } else {
#pragma unroll 1
            for (int P = 0; P < 4; ++P) {
                const short* bpf = bb + P * 2048 + l * 8;
                const short* bpc = bb + (P + 4) * 2048 + l * 8;
                bf16x8 Bf0 = *(const bf16x8*)(bpf);
                bf16x8 Bf1 = *(const bf16x8*)(bpf + 512);
                bf16x8 Bf2 = *(const bf16x8*)(bpf + 1024);
                bf16x8 Bf3 = *(const bf16x8*)(bpf + 1536);
                bf16x8 Bc0 = *(const bf16x8*)(bpc);
                bf16x8 Bc1 = *(const bf16x8*)(bpc + 512);
                bf16x8 Bc2 = *(const bf16x8*)(bpc + 1024);
                bf16x8 Bc3 = *(const bf16x8*)(bpc + 1536);
                const int c = P * 16 + lo;
                const float s_f = sc_s[c], h_f = sh_s[c];
                const float s_c = sc_s[64 + c], h_c = sh_s[64 + c];
                float hv0f = bf2f((unsigned short)aSS[(long)a0 * C2 + c]) * s_f + h_f;
                float hv0c = bf2f((unsigned short)aSS[(long)a0 * C2 + 64 + c]) * s_c + h_c;
                float hv1f = bf2f((unsigned short)aSS[(long)a1 * C2 + c]) * s_f + h_f;
                float hv1c = bf2f((unsigned short)aSS[(long)a1 * C2 + 64 + c]) * s_c + h_c;
                f32x4 zf0 = {0.f, 0.f, 0.f, 0.f}, zc0 = {0.f, 0.f, 0.f, 0.f};
                f32x4 zf1 = {0.f, 0.f, 0.f, 0.f}, zc1 = {0.f, 0.f, 0.f, 0.f};
                zf0 = __builtin_amdgcn_mfma_f32_16x16x32_bf16(A00, Bf0, zf0, 0, 0, 0);
                zc0 = __builtin_amdgcn_mfma_f32_16x16x32_bf16(A00, Bc0, zc0, 0, 0, 0);
                zf1 = __builtin_amdgcn_mfma_f32_16x16x32_bf16(A10, Bf0, zf1, 0, 0, 0);
                zc1 = __builtin_amdgcn_mfma_f32_16x16x32_bf16(A10, Bc0, zc1, 0, 0, 0);
                zf0 = __builtin_amdgcn_mfma_f32_16x16x32_bf16(A01, Bf1, zf0, 0, 0, 0);
                zc0 = __builtin_amdgcn_mfma_f32_16x16x32_bf16(A01, Bc1, zc0, 0, 0, 0);
                zf1 = __builtin_amdgcn_mfma_f32_16x16x32_bf16(A11, Bf1, zf1, 0, 0, 0);
                zc1 = __builtin_amdgcn_mfma_f32_16x16x32_bf16(A11, Bc1, zc1, 0, 0, 0);
                zf0 = __builtin_amdgcn_mfma_f32_16x16x32_bf16(A02, Bf2, zf0, 0, 0, 0);
                zc0 = __builtin_amdgcn_mfma_f32_16x16x32_bf16(A02, Bc2, zc0, 0, 0, 0);
                zf1 = __builtin_amdgcn_mfma_f32_16x16x32_bf16(A12, Bf2, zf1, 0, 0, 0);
                zc1 = __builtin_amdgcn_mfma_f32_16x16x32_bf16(A12, Bc2, zc1, 0, 0, 0);
                zf0 = __builtin_amdgcn_mfma_f32_16x16x32_bf16(A03, Bf3, zf0, 0, 0, 0);
                zc0 = __builtin_amdgcn_mfma_f32_16x16x32_bf16(A03, Bc3, zc0, 0, 0, 0);
                zf1 = __builtin_amdgcn_mfma_f32_16x16x32_bf16(A13, Bf3, zf1, 0, 0, 0);
                zc1 = __builtin_amdgcn_mfma_f32_16x16x32_bf16(A13, Bc3, zc1, 0, 0, 0);
#pragma unroll
                for (int g = 0; g < 2; ++g) {
                    f32x4 zf = g ? zf1 : zf0;
                    f32x4 zc = g ? zc1 : zc0;
                    float hvf = g ? hv1f : hv0f;
                    float hvc = g ? hv1c : hv0c;
                    float pvsum = 0.f;
#pragma unroll
                    for (int qq = 0; qq < 4; ++qq) {
                        float zfh = zf[qq] * s_f + hvf;
                        float zch = zc[qq] * s_c + hvc;
                        float filt = 1.f / (1.f + __expf(-zfh));
                        pvsum += filt * softplus_f(zch);
                    }
                    if (hi == 3) pvsum = 0.f;
                    pvsum += __shfl_xor(pvsum, 16);
                    pvsum += __shfl_xor(pvsum, 32);
                    if (hi == 0) {
                        sout[(long)(g ? a1 : a0) * FDIM + c] = pvsum;
                        atomicAdd(&bn_s[c], pvsum);
                        atomicAdd(&bn_s[64 + c], pvsum * pvsum);
                    }
                }
            }
        }
    }

    __syncthreads();
    if (APPLY == 0) {
        atomicAdd(&bn1_slots[(blockIdx.x & 63) * 256 + t], bn_s[t]);
    } else {
        if (t < 128)
            atomicAdd(&bn2_slots[(blockIdx.x & 63) * 128 + t], bn_s[t]);
    }
}

__global__ void k_pool(const float* __restrict__ x, const int* __restrict__ seg,
                       float* __restrict__ cry, float* __restrict__ cnt) {
    long i = (long)blockIdx.x * 256 + threadIdx.x;
    if (i >= (long)NATOM * FDIM) return;
    int n = (int)(i >> 6), c = (int)(i & 63);
    int cr = seg[n];
    atomicAdd(&cry[(long)cr * FDIM + c], x[i]);
    if (c == 0) atomicAdd(&cnt[cr], 1.f);
}

__global__ __launch_bounds__(256)
void k_head(const float* __restrict__ cry, const float* __restrict__ cnt,
            const float* __restrict__ fw, const float* __restrict__ fb,
            const float* __restrict__ hw, const float* __restrict__ hb,
            const float* __restrict__ ow, const float* __restrict__ ob,
            float* __restrict__ out) {
    __shared__ float cs[64], h1[128], red[256];
    int t = threadIdx.x, cr = blockIdx.x;
    if (t < 64) cs[t] = cry[(long)cr * 64 + t] / fmaxf(cnt[cr], 1.f);
    __syncthreads();
    if (t < 128) {
        float a = fb[t];
        for (int k = 0; k < 64; ++k) a += cs[k] * fw[k * 128 + t];
        h1[t] = fmaxf(a, 0.f);
    }
    __syncthreads();
    float a = hb[t];
    for (int k = 0; k < 128; ++k) a += h1[k] * hw[k * 256 + t];
    red[t] = a * ow[t];
    __syncthreads();
    for (int off = 128; off > 0; off >>= 1) {
        if (t < off) red[t] += red[t + off];
        __syncthreads();
    }
    if (t == 0) out[cr] = red[0] + ob[0];
}

extern "C" void kernel_launch(void* const* d_in, const int* in_sizes, int n_in,
                              void* d_out, int out_size, void* d_ws, size_t ws_size,
                              hipStream_t stream) {
    const float* atom_fea = (const float*)d_in[0];
    const float* nbr_fea  = (const float*)d_in[1];
    const int*   nbr_idx  = (const int*)d_in[2];
    const int*   seg      = (const int*)d_in[3];
    const float* emb_w    = (const float*)d_in[4];
    const float* emb_b    = (const float*)d_in[5];
    const float* conv_w   = (const float*)d_in[6];
    const float* bn1_g    = (const float*)d_in[8];
    const float* bn1_b    = (const float*)d_in[9];
    const float* bn2_g    = (const float*)d_in[10];
    const float* bn2_b    = (const float*)d_in[11];
    const float* fc_w     = (const float*)d_in[12];
    const float* fc_b     = (const float*)d_in[13];
    const float* head_w   = (const float*)d_in[14];
    const float* head_b   = (const float*)d_in[15];
    const float* out_w    = (const float*)d_in[16];
    const float* out_b    = (const float*)d_in[17];
    float* out = (float*)d_out;

    float* ws = (float*)d_ws;
    float* x = ws + X_OFF;
    __hip_bfloat16* xb     = (__hip_bfloat16*)(ws + XB_OFF);
    float* s = ws + S_OFF;
    __hip_bfloat16* nbrb   = (__hip_bfloat16*)(ws + NBRB_OFF);
    __hip_bfloat16* aS     = (__hip_bfloat16*)(ws + AS_OFF);
    __hip_bfloat16* ballf  = (__hip_bfloat16*)(ws + BALL_OFF);
    __hip_bfloat16* ballfS = (__hip_bfloat16*)(ws + BALLS_OFF);
    float* bn1s = ws + BN1S_OFF;
    float* bn2s = ws + BN2S_OFF;
    float* cry = ws + CRY_OFF;
    float* cnt = ws + CNT_OFF;
    float* sc1 = ws + SC1_OFF;
    float* sh1 = ws + SH1_OFF;
    __hip_bfloat16* zb = (__hip_bfloat16*)(ws + ZB_OFF);
    const bool fused = (ws_size >= (size_t)WS_NEED_FUSED);

    k_zero<<<(int)((ZERO_CNT + 255) / 256), 256, 0, stream>>>(ws + ZERO_OFF, ZERO_CNT);
    k_nbrcvt<<<(int)(((long)NEDGE * 6 + 255) / 256), 256, 0, stream>>>(nbr_fea, nbrb);
    k_embed<<<NATOM / 16, 256, 0, stream>>>(atom_fea, emb_w, emb_b, x, xb);

    for (int i = 0; i < 3; ++i) {
        const float* cw = conv_w + (long)i * 169 * C2;
        float* bn1L = bn1s + (long)i * 16384;
        float* bn2L = bn2s + (long)i * 8192;
        k_bcvt<<<96, 256, 0, stream>>>(cw, ballf, ballfS);
        k_lin<<<1563, 256, 0, stream>>>(xb, ballfS, aS);
        if (fused) {
            k_edge_dense<<<9375, 256, 0, stream>>>(xb, nbrb, ballf, aS, nbr_idx, bn1L, zb);
            k_zapply2<<<2048, 256, 0, stream>>>(zb, bn1L, bn1_g + i * C2, bn1_b + i * C2,
                                                s, bn2L);
        } else {
            k_edge<0><<<NATOM / 16, 256, 0, stream>>>(xb, nbrb, ballf, aS, nbr_idx,
                                                      nullptr, nullptr, bn1L, nullptr, nullptr);
            k_bnfin<<<1, 128, 0, stream>>>(bn1L, bn1_g + i * C2, bn1_b + i * C2,
                                           sc1, sh1, 1.f / 1200000.f, 128);
            k_edge<1><<<NATOM / 16, 256, 0, stream>>>(xb, nbrb, ballf, aS, nbr_idx,
                                                      sc1, sh1, nullptr, s, bn2L);
        }
        k_x<<<2048, 256, 0, stream>>>(x, xb, s, bn2L, bn2_g + i * 64, bn2_b + i * 64);
    }

    k_pool<<<(NATOM * FDIM) / 256, 256, 0, stream>>>(x, seg, cry, cnt);
    k_head<<<2000, 256, 0, stream>>>(cry, cnt, fc_w, fc_b, head_w, head_b, out_w, out_b, out);
}